// Round 14
// baseline (5540.574 us; speedup 1.0000x reference)
//
#include <hip/hip_runtime.h>
#include <math.h>

// ---------------------------------------------------------------------------
// RPN pipeline — hypothesis: np ref = f64 conv -> h stored f32 -> f64 head ->
// LOGITS stored f32 -> f64 softmax (upcast) -> f64 fg ordering (tie-free).
// Box/NMS = faithful f32 (proven insensitive).
// Outputs (f32, concatenated):
//   [0]        rpn_locs   147456 x 4
//   [589824]   rpn_scores 147456 x 2
//   [884736]   roi_out      2000 x 4
//   [892736]   anchors    147456 x 4
// ---------------------------------------------------------------------------

#define NPX    16384
#define NANCH  147456
#define NSEL   12000
#define NW     188
#define NPOST  2000
#define MCAP   16384

static const size_t WS_HT    = 0;                      // f32 h: 16384*512*4 = 33554432
static const size_t WS_MASK  = 0;                      // overlays HT after head_k (18MB)
static const size_t WS_KEY   = 33554432;               // 147456*4
static const size_t WS_WT    = WS_KEY  + 589824;       // f32 512*64*4 = 131072
static const size_t WS_FGD   = WS_WT   + 131072;       // f64 147456*8 = 1179648
static const size_t WS_ZERO0 = WS_FGD  + 1179648;      // ---- zeroed ----
static const size_t WS_HIST1 = WS_ZERO0;               // 262144
static const size_t WS_HIST2 = WS_HIST1 + 262144;      // 262144
static const size_t WS_CTRL  = WS_HIST2 + 262144;      // 256
static const size_t WS_ZEND  = WS_CTRL  + 256;         // ---- end zeroed ----
static const size_t WS_SELI  = WS_ZEND;                // 65536
static const size_t WS_SELD  = WS_SELI + 65536;        // 131072
static const size_t WS_SORT  = WS_SELD + 131072;       // 48128
static const size_t WS_BOX   = WS_SORT + 48128;        // f32 192256
static const size_t WS_AREA  = WS_BOX  + 192256;       // 48128
static const size_t WS_VALID = WS_AREA + 48128;        // 48128
static const size_t WS_KEEP  = WS_VALID + 48128;       // 1536

// ---------------------------------------------------------------------------
// 3x3 conv 512->512, SAME, fp64 accumulation + f64 bias/leaky, CAST TO F32.
// ---------------------------------------------------------------------------
__global__ __launch_bounds__(256) void conv3_k(const float* __restrict__ x,
                                               const float* __restrict__ w,
                                               const float* __restrict__ bias,
                                               float* __restrict__ ht)
{
    __shared__ float  xs[8][18][20];
    __shared__ double wsm[8][16][10];
    const int tid = threadIdx.x;
    const int og  = tid >> 6;
    const int q   = tid & 63;
    const int qy  = q >> 3, qx = q & 7;
    const int bx  = blockIdx.x;
    const int ocb = blockIdx.y * 16;
    const int py0 = (bx >> 3) * 16;
    const int px0 = (bx & 7) * 16;

    double acc[2][2][4];
#pragma unroll
    for (int i = 0; i < 2; i++)
#pragma unroll
        for (int j = 0; j < 2; j++)
#pragma unroll
            for (int o = 0; o < 4; o++) acc[i][j][o] = 0.0;

    for (int cb = 0; cb < 512; cb += 8) {
        for (int t = tid; t < 8 * 18 * 18; t += 256) {
            int cc = t / 324; int rem = t - cc * 324;
            int row = rem / 18; int col = rem - row * 18;
            int gy = py0 - 1 + row, gx = px0 - 1 + col;
            float v = 0.f;
            if ((unsigned)gy < 128u && (unsigned)gx < 128u)
                v = x[(size_t)(cb + cc) * 16384 + gy * 128 + gx];
            xs[cc][row][col] = v;
        }
        if (tid < 128) {
            int ocw = tid & 15, ccw = tid >> 4;
            const float* wp = w + ((size_t)(ocb + ocw) * 512 + (cb + ccw)) * 9;
#pragma unroll
            for (int k = 0; k < 9; k++) wsm[ccw][ocw][k] = (double)wp[k];
        }
        __syncthreads();
#pragma unroll
        for (int cc = 0; cc < 8; ++cc) {
            double xd[4][4];
#pragma unroll
            for (int r = 0; r < 4; r++) {
                const float2* xp = (const float2*)&xs[cc][qy * 2 + r][qx * 2];
                float2 u0 = xp[0], u1 = xp[1];
                xd[r][0] = (double)u0.x; xd[r][1] = (double)u0.y;
                xd[r][2] = (double)u1.x; xd[r][3] = (double)u1.y;
            }
#pragma unroll
            for (int o = 0; o < 4; o++) {
                const double* wr = &wsm[cc][og * 4 + o][0];
                double wk[9];
#pragma unroll
                for (int k = 0; k < 9; k++) wk[k] = wr[k];
#pragma unroll
                for (int iy = 0; iy < 2; iy++)
#pragma unroll
                    for (int ix = 0; ix < 2; ix++) {
                        double s = acc[iy][ix][o];
                        s = fma(xd[iy + 0][ix + 0], wk[0], s);
                        s = fma(xd[iy + 0][ix + 1], wk[1], s);
                        s = fma(xd[iy + 0][ix + 2], wk[2], s);
                        s = fma(xd[iy + 1][ix + 0], wk[3], s);
                        s = fma(xd[iy + 1][ix + 1], wk[4], s);
                        s = fma(xd[iy + 1][ix + 2], wk[5], s);
                        s = fma(xd[iy + 2][ix + 0], wk[6], s);
                        s = fma(xd[iy + 2][ix + 1], wk[7], s);
                        s = fma(xd[iy + 2][ix + 2], wk[8], s);
                        acc[iy][ix][o] = s;
                    }
            }
        }
        __syncthreads();
    }
    double bv[4];
#pragma unroll
    for (int o = 0; o < 4; o++) bv[o] = (double)bias[ocb + og * 4 + o];
#pragma unroll
    for (int iy = 0; iy < 2; iy++)
#pragma unroll
        for (int ix = 0; ix < 2; ix++) {
            int y = py0 + qy * 2 + iy, xx = px0 + qx * 2 + ix;
            size_t p = (size_t)y * 128 + xx;
            float o0[4];
#pragma unroll
            for (int o = 0; o < 4; o++) {
                double v = acc[iy][ix][o] + bv[o];
                double lv = (v >= 0.0) ? v : 0.01 * v;
                o0[o] = (float)lv;                    // h materialized f32
            }
            float4* dst = (float4*)(ht + p * 512 + ocb + og * 4);
            dst[0] = make_float4(o0[0], o0[1], o0[2], o0[3]);
        }
}

__global__ __launch_bounds__(256) void wt_build_k(const float* __restrict__ lw,
                                                  const float* __restrict__ sw,
                                                  float* __restrict__ wT)
{
    int i = blockIdx.x * 256 + threadIdx.x;
    if (i >= 512 * 64) return;
    int c = i >> 6, k = i & 63;
    float v = 0.f;
    if (k < 36) v = lw[(size_t)k * 512 + c];
    else if (k < 54) v = sw[(size_t)(k - 36) * 512 + c];
    wT[(size_t)c * 64 + k] = v;
}

// 1x1 heads: f64 accumulation over f32 h; LOGITS cast to f32; f64 softmax
// on upcast logits; f64 fg + f32 key out.
__global__ __launch_bounds__(256) void head_k(const float* __restrict__ ht,
                                              const float* __restrict__ wT,
                                              const float* __restrict__ locb,
                                              const float* __restrict__ scoreb,
                                              float* __restrict__ out_locs,
                                              float* __restrict__ out_scores,
                                              double* __restrict__ fgd,
                                              unsigned* __restrict__ key)
{
    __shared__ float hrow[4][512];
    const int tid = threadIdx.x;
    const int lw = tid >> 6, lane = tid & 63;
    for (int it = 0; it < 2; ++it) {
        int p = (blockIdx.x * 4 + lw) * 2 + it;
        const float4* hp = (const float4*)(ht + (size_t)p * 512);
        float4 v0 = hp[lane];
        float4 v1 = hp[lane + 64];
        ((float4*)hrow[lw])[lane] = v0;
        ((float4*)hrow[lw])[lane + 64] = v1;
        __syncthreads();
        double acc = 0.0;
        const float* hr = hrow[lw];
        for (int c4 = 0; c4 < 128; c4++) {
            float4 h4 = ((const float4*)hr)[c4];
            float w0 = wT[(size_t)(c4 * 4 + 0) * 64 + lane];
            float w1 = wT[(size_t)(c4 * 4 + 1) * 64 + lane];
            float w2 = wT[(size_t)(c4 * 4 + 2) * 64 + lane];
            float w3 = wT[(size_t)(c4 * 4 + 3) * 64 + lane];
            acc = fma((double)h4.x, (double)w0, acc);
            acc = fma((double)h4.y, (double)w1, acc);
            acc = fma((double)h4.z, (double)w2, acc);
            acc = fma((double)h4.w, (double)w3, acc);
        }
        if (lane < 36) {
            out_locs[(size_t)p * 36 + lane] = (float)(acc + (double)locb[lane]);
        } else if (lane < 54) {
            int ch = lane - 36;
            float svf = (float)(acc + (double)scoreb[ch]);  // logits stored f32
            double sv = (double)svf;                        // softmax upcast f64
            double ov = __shfl(sv, lane ^ 1);
            double s0 = (ch & 1) ? ov : sv;
            double s1 = (ch & 1) ? sv : ov;
            double m = fmax(s0, s1);
            double e0 = exp(s0 - m), e1 = exp(s1 - m);
            double den = e0 + e1;
            double my = ((ch & 1) ? e1 : e0) / den;         // fg stays f64
            out_scores[(size_t)p * 18 + ch] = (float)my;
            if (ch & 1) {
                fgd[(size_t)p * 9 + (ch >> 1)] = my;
                key[(size_t)p * 9 + (ch >> 1)] = __float_as_uint((float)my);
            }
        }
        __syncthreads();
    }
}

__global__ __launch_bounds__(256) void hist1_k(const unsigned* __restrict__ key,
                                               unsigned* __restrict__ hist)
{
    int i = blockIdx.x * 256 + threadIdx.x;
    if (i < NANCH) atomicAdd(&hist[key[i] >> 16], 1u);
}

__global__ __launch_bounds__(256) void hist2_k(const unsigned* __restrict__ key,
                                               const unsigned* __restrict__ ctrl,
                                               unsigned* __restrict__ hist)
{
    int i = blockIdx.x * 256 + threadIdx.x;
    if (i < NANCH) {
        unsigned k = key[i];
        if ((k >> 16) == ctrl[2]) atomicAdd(&hist[k & 0xffffu], 1u);
    }
}

__global__ __launch_bounds__(256) void scan_k(const unsigned* __restrict__ hist,
                                              unsigned* __restrict__ ctrl, int mode)
{
    __shared__ unsigned csum[256];
    __shared__ unsigned binv[256];
    __shared__ int sChunk;
    __shared__ unsigned sAcc;
    int tid = threadIdx.x;
    unsigned base = (mode == 0) ? 0u : ctrl[3];
    unsigned s = 0;
    for (int b = 0; b < 256; ++b) s += hist[tid * 256 + b];
    csum[tid] = s;
    __syncthreads();
    if (tid == 0) {
        unsigned acc = base; int c = 0;
        for (int t = 255; t >= 0; --t) {
            if (acc + csum[t] >= (unsigned)NSEL) { c = t; break; }
            acc += csum[t];
        }
        sChunk = c; sAcc = acc;
    }
    __syncthreads();
    int c = sChunk;
    binv[tid] = hist[c * 256 + tid];
    __syncthreads();
    if (tid == 0) {
        unsigned acc = sAcc; int bsel = 0;
        for (int t = 255; t >= 0; --t) {
            if (acc + binv[t] >= (unsigned)NSEL) { bsel = t; break; }
            acc += binv[t];
        }
        unsigned binidx = (unsigned)(c * 256 + bsel);
        if (mode == 0) { ctrl[2] = binidx; ctrl[3] = acc; }
        else           { ctrl[4] = (ctrl[2] << 16) | binidx; }
    }
}

__global__ __launch_bounds__(256) void compact_k(const unsigned* __restrict__ key,
                                                 const double* __restrict__ fgd,
                                                 unsigned* __restrict__ ctrl,
                                                 unsigned* __restrict__ seli,
                                                 double* __restrict__ seld)
{
    int i = blockIdx.x * 256 + threadIdx.x;
    if (i >= NANCH) return;
    unsigned k = key[i], T = ctrl[4];
    if (k >= T) {
        unsigned pos = atomicAdd(&ctrl[0], 1u);
        if (pos < (unsigned)MCAP) { seli[pos] = (unsigned)i; seld[pos] = fgd[i]; }
    }
}

// exact rank among candidates by (f64 fg desc, idx asc)
__global__ __launch_bounds__(256) void ranksort_k(const unsigned* __restrict__ ctrl,
                                                  const unsigned* __restrict__ seli,
                                                  const double* __restrict__ seld,
                                                  unsigned* __restrict__ sorted)
{
    __shared__ double  sd[1024];
    __shared__ unsigned si[1024];
    int i = blockIdx.x * 256 + threadIdx.x;
    unsigned M = ctrl[0]; if (M > (unsigned)MCAP) M = (unsigned)MCAP;
    double di = 0.0; unsigned ii = 0xFFFFFFFFu;
    if (i < (int)M) { di = seld[i]; ii = seli[i]; }
    unsigned r = 0;
    for (unsigned t0 = 0; t0 < M; t0 += 1024) {
        unsigned tn = (M - t0 < 1024u) ? (M - t0) : 1024u;
        __syncthreads();
        for (unsigned t = threadIdx.x; t < tn; t += 256) { sd[t] = seld[t0 + t]; si[t] = seli[t0 + t]; }
        __syncthreads();
        if (i < (int)M) {
            for (unsigned t = 0; t < tn; ++t) {
                double dj = sd[t];
                r += (dj > di || (dj == di && si[t] < ii)) ? 1u : 0u;
            }
        }
    }
    if (i < (int)M && r < (unsigned)NSEL) sorted[r] = ii;
}

// faithful-f32 box path (proven insensitive)
__global__ __launch_bounds__(256) void box_k(const unsigned* __restrict__ sorted,
                                             const float* __restrict__ locs,
                                             const int* __restrict__ img_h,
                                             const int* __restrict__ img_w,
                                             float* __restrict__ boxes,
                                             float* __restrict__ area,
                                             unsigned* __restrict__ valid)
{
    int i = blockIdx.x * 256 + threadIdx.x;
    if (i >= NSEL) return;
    unsigned src = sorted[i];
    int a = src % 9; int p = src / 9; int gx = p & 127; int gy = p >> 7;
    int ri = a / 3, si = a - ri * 3;
    double rr = (ri == 0) ? 0.5 : ((ri == 1) ? 1.0 : 2.0);
    double ss = (si == 0) ? 8.0 : ((si == 1) ? 16.0 : 32.0);
    double bh = 16.0 * ss * sqrt(rr);
    double bw = 16.0 * ss * sqrt(1.0 / rr);
    float b0 = (float)(-bh / 2.0), b1 = (float)(-bw / 2.0);
    float b2 = (float)(bh / 2.0),  b3 = (float)(bw / 2.0);
    float cy = (float)(gy * 16 + 8), cx = (float)(gx * 16 + 8);
    float a0 = __fadd_rn(cy, b0), a1 = __fadd_rn(cx, b1);
    float a2 = __fadd_rn(cy, b2), a3 = __fadd_rn(cx, b3);
    float ah = __fsub_rn(a2, a0), aw = __fsub_rn(a3, a1);
    float acy = __fadd_rn(a0, __fmul_rn(0.5f, ah));
    float acx = __fadd_rn(a1, __fmul_rn(0.5f, aw));
    const float* lp = locs + (size_t)src * 4;
    float dy = lp[0], dx = lp[1], dh = lp[2], dw = lp[3];
    float ncy = __fadd_rn(__fmul_rn(dy, ah), acy);
    float ncx = __fadd_rn(__fmul_rn(dx, aw), acx);
    float edh = (float)exp((double)dh);
    float edw = (float)exp((double)dw);
    float hh  = __fmul_rn(ah, edh);
    float wwv = __fmul_rn(aw, edw);
    float y1 = __fsub_rn(ncy, __fmul_rn(0.5f, hh));
    float x1 = __fsub_rn(ncx, __fmul_rn(0.5f, wwv));
    float y2 = __fadd_rn(ncy, __fmul_rn(0.5f, hh));
    float x2 = __fadd_rn(ncx, __fmul_rn(0.5f, wwv));
    float ihf = (float)img_h[0], iwf = (float)img_w[0];
    y1 = fminf(fmaxf(y1, 0.f), ihf);
    x1 = fminf(fmaxf(x1, 0.f), iwf);
    y2 = fminf(fmaxf(y2, 0.f), ihf);
    x2 = fminf(fmaxf(x2, 0.f), iwf);
    float dyv = __fsub_rn(y2, y1), dxv = __fsub_rn(x2, x1);
    unsigned v = (dyv >= 16.f && dxv >= 16.f) ? 1u : 0u;
    boxes[(size_t)i * 4 + 0] = y1;
    boxes[(size_t)i * 4 + 1] = x1;
    boxes[(size_t)i * 4 + 2] = y2;
    boxes[(size_t)i * 4 + 3] = x2;
    area[i] = __fmul_rn(dyv, dxv);
    valid[i] = v;
}

__global__ __launch_bounds__(64) void mask_k(const float* __restrict__ boxes,
                                             const float* __restrict__ area,
                                             const unsigned* __restrict__ valid,
                                             unsigned long long* __restrict__ mask)
{
    int gyb = blockIdx.y, gxb = blockIdx.x;
    if (gxb < gyb) return;
    __shared__ float bj[64][4];
    __shared__ float aj[64];
    int t = threadIdx.x;
    int j = gxb * 64 + t;
    if (j < NSEL) {
        bj[t][0] = boxes[(size_t)j * 4 + 0];
        bj[t][1] = boxes[(size_t)j * 4 + 1];
        bj[t][2] = boxes[(size_t)j * 4 + 2];
        bj[t][3] = boxes[(size_t)j * 4 + 3];
        aj[t] = area[j];
    }
    __syncthreads();
    int r = gyb * 64 + t;
    if (r >= NSEL) return;
    unsigned long long wbits = 0ull;
    if (valid[r]) {
        float ry1 = boxes[(size_t)r * 4 + 0], rx1 = boxes[(size_t)r * 4 + 1];
        float ry2 = boxes[(size_t)r * 4 + 2], rx2 = boxes[(size_t)r * 4 + 3];
        float ra = area[r];
        int jmax = min(64, NSEL - gxb * 64);
        for (int jj = 0; jj < jmax; ++jj) {
            int jidx = gxb * 64 + jj;
            if (jidx <= r) continue;
            float yy1 = fmaxf(ry1, bj[jj][0]);
            float xx1 = fmaxf(rx1, bj[jj][1]);
            float yy2 = fminf(ry2, bj[jj][2]);
            float xx2 = fminf(rx2, bj[jj][3]);
            float ihh = fmaxf(__fsub_rn(yy2, yy1), 0.f);
            float iww = fmaxf(__fsub_rn(xx2, xx1), 0.f);
            float inter = __fmul_rn(ihh, iww);
            float denom = __fadd_rn(__fsub_rn(__fadd_rn(ra, aj[jj]), inter), 1e-10f);
            float iou = inter / denom;
            if (iou > 0.7f) wbits |= (1ull << jj);
        }
    }
    mask[(size_t)r * NW + gxb] = wbits;
}

__global__ __launch_bounds__(256) void nmsreduce_k(const unsigned long long* __restrict__ mask,
                                                   const unsigned* __restrict__ valid,
                                                   unsigned long long* __restrict__ keepw)
{
    __shared__ unsigned long long supp[NW];
    __shared__ unsigned long long validw[NW];
    __shared__ unsigned long long dmS[64];
    __shared__ unsigned long long aliveS;
    int tid = threadIdx.x;
    for (int g = tid; g < NW; g += 256) {
        unsigned long long w = 0ull;
        int r0 = g * 64, lim = min(64, NSEL - r0);
        for (int b = 0; b < lim; ++b)
            if (valid[r0 + b]) w |= (1ull << b);
        validw[g] = w; supp[g] = 0ull;
    }
    __syncthreads();
    for (int g = 0; g < NW; ++g) {
        if (tid < 64) {
            int r = g * 64 + tid;
            dmS[tid] = (r < NSEL) ? mask[(size_t)r * NW + g] : 0ull;
        }
        __syncthreads();
        if (tid < 64) {
            unsigned long long m = dmS[tid];
            unsigned long long w = supp[g];
            unsigned long long cand = ~w;
            while (cand) {
                int b = __ffsll((unsigned long long)cand) - 1;
                unsigned long long vb = __shfl(m, b);
                w |= vb;
                cand = (b >= 63) ? 0ull : (~w & (~0ull << (b + 1)));
            }
            if (tid == 0) { supp[g] = w; aliveS = ~w & validw[g]; }
        }
        __syncthreads();
        unsigned long long av = aliveS;
        for (int g2 = g + 1 + tid; g2 < NW; g2 += 256) {
            unsigned long long accv = supp[g2];
            unsigned long long aa = av;
            while (aa) {
                int b = __ffsll((unsigned long long)aa) - 1;
                aa &= aa - 1;
                accv |= mask[(size_t)(g * 64 + b) * NW + g2];
            }
            supp[g2] = accv;
        }
        __syncthreads();
    }
    for (int g = tid; g < NW; g += 256) keepw[g] = ~supp[g] & validw[g];
}

__global__ __launch_bounds__(256) void out_k(const unsigned long long* __restrict__ keepw,
                                             const float* __restrict__ boxes,
                                             float* __restrict__ out2)
{
    __shared__ unsigned pref[NW + 1];
    int tid = threadIdx.x;
    for (int t = tid; t < NPOST * 4; t += 256) out2[t] = 0.f;
    __syncthreads();
    if (tid == 0) {
        unsigned acc = 0;
        for (int g = 0; g < NW; ++g) { pref[g] = acc; acc += __popcll(keepw[g]); }
        pref[NW] = acc;
    }
    __syncthreads();
    for (int r = tid; r < NSEL; r += 256) {
        int g = r >> 6, b = r & 63;
        unsigned long long w = keepw[g];
        if ((w >> b) & 1ull) {
            unsigned rk = pref[g] + (unsigned)__popcll(w & ((1ull << b) - 1ull));
            if (rk < NPOST) {
                out2[(size_t)rk * 4 + 0] = boxes[(size_t)r * 4 + 0];
                out2[(size_t)rk * 4 + 1] = boxes[(size_t)r * 4 + 1];
                out2[(size_t)rk * 4 + 2] = boxes[(size_t)r * 4 + 2];
                out2[(size_t)rk * 4 + 3] = boxes[(size_t)r * 4 + 3];
            }
        }
    }
}

__global__ __launch_bounds__(256) void anchors_k(float* __restrict__ out3)
{
    int i = blockIdx.x * 256 + threadIdx.x;
    if (i >= NANCH) return;
    int a = i % 9; int p = i / 9; int gx = p & 127, gy = p >> 7;
    int ri = a / 3, si = a - ri * 3;
    double rr = (ri == 0) ? 0.5 : ((ri == 1) ? 1.0 : 2.0);
    double ss = (si == 0) ? 8.0 : ((si == 1) ? 16.0 : 32.0);
    double bh = 16.0 * ss * sqrt(rr);
    double bw = 16.0 * ss * sqrt(1.0 / rr);
    float b0 = (float)(-bh / 2.0), b1 = (float)(-bw / 2.0);
    float b2 = (float)(bh / 2.0),  b3 = (float)(bw / 2.0);
    float cy = (float)(gy * 16 + 8), cx = (float)(gx * 16 + 8);
    out3[(size_t)i * 4 + 0] = cy + b0;
    out3[(size_t)i * 4 + 1] = cx + b1;
    out3[(size_t)i * 4 + 2] = cy + b2;
    out3[(size_t)i * 4 + 3] = cx + b3;
}

extern "C" void kernel_launch(void* const* d_in, const int* in_sizes, int n_in,
                              void* d_out, int out_size, void* d_ws, size_t ws_size,
                              hipStream_t stream)
{
    const float* x       = (const float*)d_in[0];
    const float* conv_w  = (const float*)d_in[1];
    const float* conv_b  = (const float*)d_in[2];
    const float* score_w = (const float*)d_in[3];
    const float* score_b = (const float*)d_in[4];
    const float* loc_w   = (const float*)d_in[5];
    const float* loc_b   = (const float*)d_in[6];
    const int*   img_h   = (const int*)d_in[7];
    const int*   img_w   = (const int*)d_in[8];

    float* out        = (float*)d_out;
    float* out_locs   = out;
    float* out_scores = out + 589824;
    float* out_roi    = out + 884736;
    float* out_anch   = out + 892736;

    char* ws = (char*)d_ws;
    float*    ht     = (float*)(ws + WS_HT);
    unsigned* key    = (unsigned*)(ws + WS_KEY);
    float*    wT     = (float*)(ws + WS_WT);
    double*   fgd    = (double*)(ws + WS_FGD);
    unsigned* hist1  = (unsigned*)(ws + WS_HIST1);
    unsigned* hist2  = (unsigned*)(ws + WS_HIST2);
    unsigned* ctrl   = (unsigned*)(ws + WS_CTRL);
    unsigned* seli   = (unsigned*)(ws + WS_SELI);
    double*   seld   = (double*)(ws + WS_SELD);
    unsigned* sorted = (unsigned*)(ws + WS_SORT);
    float*    boxes  = (float*)(ws + WS_BOX);
    float*    area   = (float*)(ws + WS_AREA);
    unsigned* valid  = (unsigned*)(ws + WS_VALID);
    unsigned long long* keepw = (unsigned long long*)(ws + WS_KEEP);
    unsigned long long* mask  = (unsigned long long*)(ws + WS_MASK);  // overlays HT

    hipMemsetAsync(ws + WS_ZERO0, 0, WS_ZEND - WS_ZERO0, stream);

    conv3_k<<<dim3(64, 32), 256, 0, stream>>>(x, conv_w, conv_b, ht);
    wt_build_k<<<128, 256, 0, stream>>>(loc_w, score_w, wT);
    head_k<<<2048, 256, 0, stream>>>(ht, wT, loc_b, score_b, out_locs, out_scores, fgd, key);
    hist1_k<<<576, 256, 0, stream>>>(key, hist1);
    scan_k<<<1, 256, 0, stream>>>(hist1, ctrl, 0);
    hist2_k<<<576, 256, 0, stream>>>(key, ctrl, hist2);
    scan_k<<<1, 256, 0, stream>>>(hist2, ctrl, 1);
    compact_k<<<576, 256, 0, stream>>>(key, fgd, ctrl, seli, seld);
    ranksort_k<<<64, 256, 0, stream>>>(ctrl, seli, seld, sorted);
    box_k<<<47, 256, 0, stream>>>(sorted, out_locs, img_h, img_w, boxes, area, valid);
    mask_k<<<dim3(NW, NW), 64, 0, stream>>>(boxes, area, valid, mask);
    nmsreduce_k<<<1, 256, 0, stream>>>(mask, valid, keepw);
    out_k<<<1, 256, 0, stream>>>(keepw, boxes, out_roi);
    anchors_k<<<576, 256, 0, stream>>>(out_anch);
}

// Round 15
// 3730.279 us; speedup vs baseline: 1.4853x; 1.4853x over previous
//
#include <hip/hip_runtime.h>
#include <math.h>

// ---------------------------------------------------------------------------
// RPN pipeline — PASSING semantics (R14): f64 conv -> h stored f32 -> f64
// head -> logits stored f32 -> f64 softmax -> f64 fg ordering. Faithful-f32
// box/NMS. This round: nmsreduce_k latency fix (alive-list propagate +
// per-group keepw + early break) — bit-identical output.
// Outputs (f32, concatenated):
//   [0]        rpn_locs   147456 x 4
//   [589824]   rpn_scores 147456 x 2
//   [884736]   roi_out      2000 x 4
//   [892736]   anchors    147456 x 4
// ---------------------------------------------------------------------------

#define NPX    16384
#define NANCH  147456
#define NSEL   12000
#define NW     188
#define NPOST  2000
#define MCAP   16384

static const size_t WS_HT    = 0;                      // f32 h: 16384*512*4 = 33554432
static const size_t WS_MASK  = 0;                      // overlays HT after head_k (18MB)
static const size_t WS_KEY   = 33554432;               // 147456*4
static const size_t WS_WT    = WS_KEY  + 589824;       // f32 512*64*4 = 131072
static const size_t WS_FGD   = WS_WT   + 131072;       // f64 147456*8 = 1179648
static const size_t WS_ZERO0 = WS_FGD  + 1179648;      // ---- zeroed ----
static const size_t WS_HIST1 = WS_ZERO0;               // 262144
static const size_t WS_HIST2 = WS_HIST1 + 262144;      // 262144
static const size_t WS_CTRL  = WS_HIST2 + 262144;      // 256
static const size_t WS_ZEND  = WS_CTRL  + 256;         // ---- end zeroed ----
static const size_t WS_SELI  = WS_ZEND;                // 65536
static const size_t WS_SELD  = WS_SELI + 65536;        // 131072
static const size_t WS_SORT  = WS_SELD + 131072;       // 48128
static const size_t WS_BOX   = WS_SORT + 48128;        // f32 192256
static const size_t WS_AREA  = WS_BOX  + 192256;       // 48128
static const size_t WS_VALID = WS_AREA + 48128;        // 48128
static const size_t WS_KEEP  = WS_VALID + 48128;       // 1536

// ---------------------------------------------------------------------------
// 3x3 conv 512->512, SAME, fp64 accumulation + f64 bias/leaky, CAST TO F32.
// ---------------------------------------------------------------------------
__global__ __launch_bounds__(256) void conv3_k(const float* __restrict__ x,
                                               const float* __restrict__ w,
                                               const float* __restrict__ bias,
                                               float* __restrict__ ht)
{
    __shared__ float  xs[8][18][20];
    __shared__ double wsm[8][16][10];
    const int tid = threadIdx.x;
    const int og  = tid >> 6;
    const int q   = tid & 63;
    const int qy  = q >> 3, qx = q & 7;
    const int bx  = blockIdx.x;
    const int ocb = blockIdx.y * 16;
    const int py0 = (bx >> 3) * 16;
    const int px0 = (bx & 7) * 16;

    double acc[2][2][4];
#pragma unroll
    for (int i = 0; i < 2; i++)
#pragma unroll
        for (int j = 0; j < 2; j++)
#pragma unroll
            for (int o = 0; o < 4; o++) acc[i][j][o] = 0.0;

    for (int cb = 0; cb < 512; cb += 8) {
        for (int t = tid; t < 8 * 18 * 18; t += 256) {
            int cc = t / 324; int rem = t - cc * 324;
            int row = rem / 18; int col = rem - row * 18;
            int gy = py0 - 1 + row, gx = px0 - 1 + col;
            float v = 0.f;
            if ((unsigned)gy < 128u && (unsigned)gx < 128u)
                v = x[(size_t)(cb + cc) * 16384 + gy * 128 + gx];
            xs[cc][row][col] = v;
        }
        if (tid < 128) {
            int ocw = tid & 15, ccw = tid >> 4;
            const float* wp = w + ((size_t)(ocb + ocw) * 512 + (cb + ccw)) * 9;
#pragma unroll
            for (int k = 0; k < 9; k++) wsm[ccw][ocw][k] = (double)wp[k];
        }
        __syncthreads();
#pragma unroll
        for (int cc = 0; cc < 8; ++cc) {
            double xd[4][4];
#pragma unroll
            for (int r = 0; r < 4; r++) {
                const float2* xp = (const float2*)&xs[cc][qy * 2 + r][qx * 2];
                float2 u0 = xp[0], u1 = xp[1];
                xd[r][0] = (double)u0.x; xd[r][1] = (double)u0.y;
                xd[r][2] = (double)u1.x; xd[r][3] = (double)u1.y;
            }
#pragma unroll
            for (int o = 0; o < 4; o++) {
                const double* wr = &wsm[cc][og * 4 + o][0];
                double wk[9];
#pragma unroll
                for (int k = 0; k < 9; k++) wk[k] = wr[k];
#pragma unroll
                for (int iy = 0; iy < 2; iy++)
#pragma unroll
                    for (int ix = 0; ix < 2; ix++) {
                        double s = acc[iy][ix][o];
                        s = fma(xd[iy + 0][ix + 0], wk[0], s);
                        s = fma(xd[iy + 0][ix + 1], wk[1], s);
                        s = fma(xd[iy + 0][ix + 2], wk[2], s);
                        s = fma(xd[iy + 1][ix + 0], wk[3], s);
                        s = fma(xd[iy + 1][ix + 1], wk[4], s);
                        s = fma(xd[iy + 1][ix + 2], wk[5], s);
                        s = fma(xd[iy + 2][ix + 0], wk[6], s);
                        s = fma(xd[iy + 2][ix + 1], wk[7], s);
                        s = fma(xd[iy + 2][ix + 2], wk[8], s);
                        acc[iy][ix][o] = s;
                    }
            }
        }
        __syncthreads();
    }
    double bv[4];
#pragma unroll
    for (int o = 0; o < 4; o++) bv[o] = (double)bias[ocb + og * 4 + o];
#pragma unroll
    for (int iy = 0; iy < 2; iy++)
#pragma unroll
        for (int ix = 0; ix < 2; ix++) {
            int y = py0 + qy * 2 + iy, xx = px0 + qx * 2 + ix;
            size_t p = (size_t)y * 128 + xx;
            float o0[4];
#pragma unroll
            for (int o = 0; o < 4; o++) {
                double v = acc[iy][ix][o] + bv[o];
                double lv = (v >= 0.0) ? v : 0.01 * v;
                o0[o] = (float)lv;                    // h materialized f32
            }
            float4* dst = (float4*)(ht + p * 512 + ocb + og * 4);
            dst[0] = make_float4(o0[0], o0[1], o0[2], o0[3]);
        }
}

__global__ __launch_bounds__(256) void wt_build_k(const float* __restrict__ lw,
                                                  const float* __restrict__ sw,
                                                  float* __restrict__ wT)
{
    int i = blockIdx.x * 256 + threadIdx.x;
    if (i >= 512 * 64) return;
    int c = i >> 6, k = i & 63;
    float v = 0.f;
    if (k < 36) v = lw[(size_t)k * 512 + c];
    else if (k < 54) v = sw[(size_t)(k - 36) * 512 + c];
    wT[(size_t)c * 64 + k] = v;
}

// 1x1 heads: f64 accumulation over f32 h; LOGITS cast to f32; f64 softmax
// on upcast logits; f64 fg + f32 key out.
__global__ __launch_bounds__(256) void head_k(const float* __restrict__ ht,
                                              const float* __restrict__ wT,
                                              const float* __restrict__ locb,
                                              const float* __restrict__ scoreb,
                                              float* __restrict__ out_locs,
                                              float* __restrict__ out_scores,
                                              double* __restrict__ fgd,
                                              unsigned* __restrict__ key)
{
    __shared__ float hrow[4][512];
    const int tid = threadIdx.x;
    const int lw = tid >> 6, lane = tid & 63;
    for (int it = 0; it < 2; ++it) {
        int p = (blockIdx.x * 4 + lw) * 2 + it;
        const float4* hp = (const float4*)(ht + (size_t)p * 512);
        float4 v0 = hp[lane];
        float4 v1 = hp[lane + 64];
        ((float4*)hrow[lw])[lane] = v0;
        ((float4*)hrow[lw])[lane + 64] = v1;
        __syncthreads();
        double acc = 0.0;
        const float* hr = hrow[lw];
        for (int c4 = 0; c4 < 128; c4++) {
            float4 h4 = ((const float4*)hr)[c4];
            float w0 = wT[(size_t)(c4 * 4 + 0) * 64 + lane];
            float w1 = wT[(size_t)(c4 * 4 + 1) * 64 + lane];
            float w2 = wT[(size_t)(c4 * 4 + 2) * 64 + lane];
            float w3 = wT[(size_t)(c4 * 4 + 3) * 64 + lane];
            acc = fma((double)h4.x, (double)w0, acc);
            acc = fma((double)h4.y, (double)w1, acc);
            acc = fma((double)h4.z, (double)w2, acc);
            acc = fma((double)h4.w, (double)w3, acc);
        }
        if (lane < 36) {
            out_locs[(size_t)p * 36 + lane] = (float)(acc + (double)locb[lane]);
        } else if (lane < 54) {
            int ch = lane - 36;
            float svf = (float)(acc + (double)scoreb[ch]);  // logits stored f32
            double sv = (double)svf;                        // softmax upcast f64
            double ov = __shfl(sv, lane ^ 1);
            double s0 = (ch & 1) ? ov : sv;
            double s1 = (ch & 1) ? sv : ov;
            double m = fmax(s0, s1);
            double e0 = exp(s0 - m), e1 = exp(s1 - m);
            double den = e0 + e1;
            double my = ((ch & 1) ? e1 : e0) / den;         // fg stays f64
            out_scores[(size_t)p * 18 + ch] = (float)my;
            if (ch & 1) {
                fgd[(size_t)p * 9 + (ch >> 1)] = my;
                key[(size_t)p * 9 + (ch >> 1)] = __float_as_uint((float)my);
            }
        }
        __syncthreads();
    }
}

__global__ __launch_bounds__(256) void hist1_k(const unsigned* __restrict__ key,
                                               unsigned* __restrict__ hist)
{
    int i = blockIdx.x * 256 + threadIdx.x;
    if (i < NANCH) atomicAdd(&hist[key[i] >> 16], 1u);
}

__global__ __launch_bounds__(256) void hist2_k(const unsigned* __restrict__ key,
                                               const unsigned* __restrict__ ctrl,
                                               unsigned* __restrict__ hist)
{
    int i = blockIdx.x * 256 + threadIdx.x;
    if (i < NANCH) {
        unsigned k = key[i];
        if ((k >> 16) == ctrl[2]) atomicAdd(&hist[k & 0xffffu], 1u);
    }
}

__global__ __launch_bounds__(256) void scan_k(const unsigned* __restrict__ hist,
                                              unsigned* __restrict__ ctrl, int mode)
{
    __shared__ unsigned csum[256];
    __shared__ unsigned binv[256];
    __shared__ int sChunk;
    __shared__ unsigned sAcc;
    int tid = threadIdx.x;
    unsigned base = (mode == 0) ? 0u : ctrl[3];
    unsigned s = 0;
    for (int b = 0; b < 256; ++b) s += hist[tid * 256 + b];
    csum[tid] = s;
    __syncthreads();
    if (tid == 0) {
        unsigned acc = base; int c = 0;
        for (int t = 255; t >= 0; --t) {
            if (acc + csum[t] >= (unsigned)NSEL) { c = t; break; }
            acc += csum[t];
        }
        sChunk = c; sAcc = acc;
    }
    __syncthreads();
    int c = sChunk;
    binv[tid] = hist[c * 256 + tid];
    __syncthreads();
    if (tid == 0) {
        unsigned acc = sAcc; int bsel = 0;
        for (int t = 255; t >= 0; --t) {
            if (acc + binv[t] >= (unsigned)NSEL) { bsel = t; break; }
            acc += binv[t];
        }
        unsigned binidx = (unsigned)(c * 256 + bsel);
        if (mode == 0) { ctrl[2] = binidx; ctrl[3] = acc; }
        else           { ctrl[4] = (ctrl[2] << 16) | binidx; }
    }
}

__global__ __launch_bounds__(256) void compact_k(const unsigned* __restrict__ key,
                                                 const double* __restrict__ fgd,
                                                 unsigned* __restrict__ ctrl,
                                                 unsigned* __restrict__ seli,
                                                 double* __restrict__ seld)
{
    int i = blockIdx.x * 256 + threadIdx.x;
    if (i >= NANCH) return;
    unsigned k = key[i], T = ctrl[4];
    if (k >= T) {
        unsigned pos = atomicAdd(&ctrl[0], 1u);
        if (pos < (unsigned)MCAP) { seli[pos] = (unsigned)i; seld[pos] = fgd[i]; }
    }
}

// exact rank among candidates by (f64 fg desc, idx asc)
__global__ __launch_bounds__(256) void ranksort_k(const unsigned* __restrict__ ctrl,
                                                  const unsigned* __restrict__ seli,
                                                  const double* __restrict__ seld,
                                                  unsigned* __restrict__ sorted)
{
    __shared__ double  sd[1024];
    __shared__ unsigned si[1024];
    int i = blockIdx.x * 256 + threadIdx.x;
    unsigned M = ctrl[0]; if (M > (unsigned)MCAP) M = (unsigned)MCAP;
    double di = 0.0; unsigned ii = 0xFFFFFFFFu;
    if (i < (int)M) { di = seld[i]; ii = seli[i]; }
    unsigned r = 0;
    for (unsigned t0 = 0; t0 < M; t0 += 1024) {
        unsigned tn = (M - t0 < 1024u) ? (M - t0) : 1024u;
        __syncthreads();
        for (unsigned t = threadIdx.x; t < tn; t += 256) { sd[t] = seld[t0 + t]; si[t] = seli[t0 + t]; }
        __syncthreads();
        if (i < (int)M) {
            for (unsigned t = 0; t < tn; ++t) {
                double dj = sd[t];
                r += (dj > di || (dj == di && si[t] < ii)) ? 1u : 0u;
            }
        }
    }
    if (i < (int)M && r < (unsigned)NSEL) sorted[r] = ii;
}

// faithful-f32 box path (proven insensitive)
__global__ __launch_bounds__(256) void box_k(const unsigned* __restrict__ sorted,
                                             const float* __restrict__ locs,
                                             const int* __restrict__ img_h,
                                             const int* __restrict__ img_w,
                                             float* __restrict__ boxes,
                                             float* __restrict__ area,
                                             unsigned* __restrict__ valid)
{
    int i = blockIdx.x * 256 + threadIdx.x;
    if (i >= NSEL) return;
    unsigned src = sorted[i];
    int a = src % 9; int p = src / 9; int gx = p & 127; int gy = p >> 7;
    int ri = a / 3, si = a - ri * 3;
    double rr = (ri == 0) ? 0.5 : ((ri == 1) ? 1.0 : 2.0);
    double ss = (si == 0) ? 8.0 : ((si == 1) ? 16.0 : 32.0);
    double bh = 16.0 * ss * sqrt(rr);
    double bw = 16.0 * ss * sqrt(1.0 / rr);
    float b0 = (float)(-bh / 2.0), b1 = (float)(-bw / 2.0);
    float b2 = (float)(bh / 2.0),  b3 = (float)(bw / 2.0);
    float cy = (float)(gy * 16 + 8), cx = (float)(gx * 16 + 8);
    float a0 = __fadd_rn(cy, b0), a1 = __fadd_rn(cx, b1);
    float a2 = __fadd_rn(cy, b2), a3 = __fadd_rn(cx, b3);
    float ah = __fsub_rn(a2, a0), aw = __fsub_rn(a3, a1);
    float acy = __fadd_rn(a0, __fmul_rn(0.5f, ah));
    float acx = __fadd_rn(a1, __fmul_rn(0.5f, aw));
    const float* lp = locs + (size_t)src * 4;
    float dy = lp[0], dx = lp[1], dh = lp[2], dw = lp[3];
    float ncy = __fadd_rn(__fmul_rn(dy, ah), acy);
    float ncx = __fadd_rn(__fmul_rn(dx, aw), acx);
    float edh = (float)exp((double)dh);
    float edw = (float)exp((double)dw);
    float hh  = __fmul_rn(ah, edh);
    float wwv = __fmul_rn(aw, edw);
    float y1 = __fsub_rn(ncy, __fmul_rn(0.5f, hh));
    float x1 = __fsub_rn(ncx, __fmul_rn(0.5f, wwv));
    float y2 = __fadd_rn(ncy, __fmul_rn(0.5f, hh));
    float x2 = __fadd_rn(ncx, __fmul_rn(0.5f, wwv));
    float ihf = (float)img_h[0], iwf = (float)img_w[0];
    y1 = fminf(fmaxf(y1, 0.f), ihf);
    x1 = fminf(fmaxf(x1, 0.f), iwf);
    y2 = fminf(fmaxf(y2, 0.f), ihf);
    x2 = fminf(fmaxf(x2, 0.f), iwf);
    float dyv = __fsub_rn(y2, y1), dxv = __fsub_rn(x2, x1);
    unsigned v = (dyv >= 16.f && dxv >= 16.f) ? 1u : 0u;
    boxes[(size_t)i * 4 + 0] = y1;
    boxes[(size_t)i * 4 + 1] = x1;
    boxes[(size_t)i * 4 + 2] = y2;
    boxes[(size_t)i * 4 + 3] = x2;
    area[i] = __fmul_rn(dyv, dxv);
    valid[i] = v;
}

__global__ __launch_bounds__(64) void mask_k(const float* __restrict__ boxes,
                                             const float* __restrict__ area,
                                             const unsigned* __restrict__ valid,
                                             unsigned long long* __restrict__ mask)
{
    int gyb = blockIdx.y, gxb = blockIdx.x;
    if (gxb < gyb) return;
    __shared__ float bj[64][4];
    __shared__ float aj[64];
    int t = threadIdx.x;
    int j = gxb * 64 + t;
    if (j < NSEL) {
        bj[t][0] = boxes[(size_t)j * 4 + 0];
        bj[t][1] = boxes[(size_t)j * 4 + 1];
        bj[t][2] = boxes[(size_t)j * 4 + 2];
        bj[t][3] = boxes[(size_t)j * 4 + 3];
        aj[t] = area[j];
    }
    __syncthreads();
    int r = gyb * 64 + t;
    if (r >= NSEL) return;
    unsigned long long wbits = 0ull;
    if (valid[r]) {
        float ry1 = boxes[(size_t)r * 4 + 0], rx1 = boxes[(size_t)r * 4 + 1];
        float ry2 = boxes[(size_t)r * 4 + 2], rx2 = boxes[(size_t)r * 4 + 3];
        float ra = area[r];
        int jmax = min(64, NSEL - gxb * 64);
        for (int jj = 0; jj < jmax; ++jj) {
            int jidx = gxb * 64 + jj;
            if (jidx <= r) continue;
            float yy1 = fmaxf(ry1, bj[jj][0]);
            float xx1 = fmaxf(rx1, bj[jj][1]);
            float yy2 = fminf(ry2, bj[jj][2]);
            float xx2 = fminf(rx2, bj[jj][3]);
            float ihh = fmaxf(__fsub_rn(yy2, yy1), 0.f);
            float iww = fmaxf(__fsub_rn(xx2, xx1), 0.f);
            float inter = __fmul_rn(ihh, iww);
            float denom = __fadd_rn(__fsub_rn(__fadd_rn(ra, aj[jj]), inter), 1e-10f);
            float iou = inter / denom;
            if (iou > 0.7f) wbits |= (1ull << jj);
        }
    }
    mask[(size_t)r * NW + gxb] = wbits;
}

// ---------------------------------------------------------------------------
// Greedy NMS reduce — OPTIMIZED (bit-identical result):
//  * per-group alive bits pre-extracted to a list -> propagate loads are an
//    independent counted loop (pipelined, not a serial dependency chain)
//  * keepw[g] written at group time (supp[g] is final then)
//  * early break once cumulative keeps >= NPOST (out_k ignores rk >= NPOST);
//    remaining keepw zeroed.
// ---------------------------------------------------------------------------
__global__ __launch_bounds__(256) void nmsreduce_k(const unsigned long long* __restrict__ mask,
                                                   const unsigned* __restrict__ valid,
                                                   unsigned long long* __restrict__ keepw)
{
    __shared__ unsigned long long supp[NW];
    __shared__ unsigned long long validw[NW];
    __shared__ unsigned long long dmS[64];
    __shared__ unsigned char aliveL[64];
    __shared__ int aliveC;
    __shared__ int keptTot;
    int tid = threadIdx.x;
    for (int g = tid; g < NW; g += 256) {
        unsigned long long w = 0ull;
        int r0 = g * 64, lim = min(64, NSEL - r0);
        for (int b = 0; b < lim; ++b)
            if (valid[r0 + b]) w |= (1ull << b);
        validw[g] = w; supp[g] = 0ull;
    }
    if (tid == 0) keptTot = 0;
    __syncthreads();
    for (int g = 0; g < NW; ++g) {
        if (tid < 64) {
            int r = g * 64 + tid;
            dmS[tid] = (r < NSEL) ? mask[(size_t)r * NW + g] : 0ull;
        }
        __syncthreads();
        if (tid < 64) {
            unsigned long long m = dmS[tid];
            unsigned long long w = supp[g];
            unsigned long long cand = ~w;
            while (cand) {
                int b = __ffsll((unsigned long long)cand) - 1;
                unsigned long long vb = __shfl(m, b);
                w |= vb;
                cand = (b >= 63) ? 0ull : (~w & (~0ull << (b + 1)));
            }
            if (tid == 0) {
                supp[g] = w;
                unsigned long long alive = ~w & validw[g];
                keepw[g] = alive;
                int c = 0;
                unsigned long long aa = alive;
                while (aa) {
                    int b = __ffsll((unsigned long long)aa) - 1;
                    aa &= aa - 1;
                    aliveL[c++] = (unsigned char)b;
                }
                aliveC = c;
                keptTot += c;
            }
        }
        __syncthreads();
        if (keptTot >= NPOST) {
            // zero remaining groups' keepw and stop — output-invariant
            for (int g2 = g + 1 + tid; g2 < NW; g2 += 256) keepw[g2] = 0ull;
            break;
        }
        int cnt = aliveC;
        if (cnt > 0) {
            const unsigned long long* mrow0 = mask + (size_t)g * 64 * NW;
            for (int g2 = g + 1 + tid; g2 < NW; g2 += 256) {
                unsigned long long acc = supp[g2];
#pragma unroll 4
                for (int bi = 0; bi < cnt; ++bi)
                    acc |= mrow0[(size_t)aliveL[bi] * NW + g2];
                supp[g2] = acc;
            }
        }
        __syncthreads();
    }
}

__global__ __launch_bounds__(256) void out_k(const unsigned long long* __restrict__ keepw,
                                             const float* __restrict__ boxes,
                                             float* __restrict__ out2)
{
    __shared__ unsigned pref[NW + 1];
    int tid = threadIdx.x;
    for (int t = tid; t < NPOST * 4; t += 256) out2[t] = 0.f;
    __syncthreads();
    if (tid == 0) {
        unsigned acc = 0;
        for (int g = 0; g < NW; ++g) { pref[g] = acc; acc += __popcll(keepw[g]); }
        pref[NW] = acc;
    }
    __syncthreads();
    for (int r = tid; r < NSEL; r += 256) {
        int g = r >> 6, b = r & 63;
        unsigned long long w = keepw[g];
        if ((w >> b) & 1ull) {
            unsigned rk = pref[g] + (unsigned)__popcll(w & ((1ull << b) - 1ull));
            if (rk < NPOST) {
                out2[(size_t)rk * 4 + 0] = boxes[(size_t)r * 4 + 0];
                out2[(size_t)rk * 4 + 1] = boxes[(size_t)r * 4 + 1];
                out2[(size_t)rk * 4 + 2] = boxes[(size_t)r * 4 + 2];
                out2[(size_t)rk * 4 + 3] = boxes[(size_t)r * 4 + 3];
            }
        }
    }
}

__global__ __launch_bounds__(256) void anchors_k(float* __restrict__ out3)
{
    int i = blockIdx.x * 256 + threadIdx.x;
    if (i >= NANCH) return;
    int a = i % 9; int p = i / 9; int gx = p & 127, gy = p >> 7;
    int ri = a / 3, si = a - ri * 3;
    double rr = (ri == 0) ? 0.5 : ((ri == 1) ? 1.0 : 2.0);
    double ss = (si == 0) ? 8.0 : ((si == 1) ? 16.0 : 32.0);
    double bh = 16.0 * ss * sqrt(rr);
    double bw = 16.0 * ss * sqrt(1.0 / rr);
    float b0 = (float)(-bh / 2.0), b1 = (float)(-bw / 2.0);
    float b2 = (float)(bh / 2.0),  b3 = (float)(bw / 2.0);
    float cy = (float)(gy * 16 + 8), cx = (float)(gx * 16 + 8);
    out3[(size_t)i * 4 + 0] = cy + b0;
    out3[(size_t)i * 4 + 1] = cx + b1;
    out3[(size_t)i * 4 + 2] = cy + b2;
    out3[(size_t)i * 4 + 3] = cx + b3;
}

extern "C" void kernel_launch(void* const* d_in, const int* in_sizes, int n_in,
                              void* d_out, int out_size, void* d_ws, size_t ws_size,
                              hipStream_t stream)
{
    const float* x       = (const float*)d_in[0];
    const float* conv_w  = (const float*)d_in[1];
    const float* conv_b  = (const float*)d_in[2];
    const float* score_w = (const float*)d_in[3];
    const float* score_b = (const float*)d_in[4];
    const float* loc_w   = (const float*)d_in[5];
    const float* loc_b   = (const float*)d_in[6];
    const int*   img_h   = (const int*)d_in[7];
    const int*   img_w   = (const int*)d_in[8];

    float* out        = (float*)d_out;
    float* out_locs   = out;
    float* out_scores = out + 589824;
    float* out_roi    = out + 884736;
    float* out_anch   = out + 892736;

    char* ws = (char*)d_ws;
    float*    ht     = (float*)(ws + WS_HT);
    unsigned* key    = (unsigned*)(ws + WS_KEY);
    float*    wT     = (float*)(ws + WS_WT);
    double*   fgd    = (double*)(ws + WS_FGD);
    unsigned* hist1  = (unsigned*)(ws + WS_HIST1);
    unsigned* hist2  = (unsigned*)(ws + WS_HIST2);
    unsigned* ctrl   = (unsigned*)(ws + WS_CTRL);
    unsigned* seli   = (unsigned*)(ws + WS_SELI);
    double*   seld   = (double*)(ws + WS_SELD);
    unsigned* sorted = (unsigned*)(ws + WS_SORT);
    float*    boxes  = (float*)(ws + WS_BOX);
    float*    area   = (float*)(ws + WS_AREA);
    unsigned* valid  = (unsigned*)(ws + WS_VALID);
    unsigned long long* keepw = (unsigned long long*)(ws + WS_KEEP);
    unsigned long long* mask  = (unsigned long long*)(ws + WS_MASK);  // overlays HT

    hipMemsetAsync(ws + WS_ZERO0, 0, WS_ZEND - WS_ZERO0, stream);

    conv3_k<<<dim3(64, 32), 256, 0, stream>>>(x, conv_w, conv_b, ht);
    wt_build_k<<<128, 256, 0, stream>>>(loc_w, score_w, wT);
    head_k<<<2048, 256, 0, stream>>>(ht, wT, loc_b, score_b, out_locs, out_scores, fgd, key);
    hist1_k<<<576, 256, 0, stream>>>(key, hist1);
    scan_k<<<1, 256, 0, stream>>>(hist1, ctrl, 0);
    hist2_k<<<576, 256, 0, stream>>>(key, ctrl, hist2);
    scan_k<<<1, 256, 0, stream>>>(hist2, ctrl, 1);
    compact_k<<<576, 256, 0, stream>>>(key, fgd, ctrl, seli, seld);
    ranksort_k<<<64, 256, 0, stream>>>(ctrl, seli, seld, sorted);
    box_k<<<47, 256, 0, stream>>>(sorted, out_locs, img_h, img_w, boxes, area, valid);
    mask_k<<<dim3(NW, NW), 64, 0, stream>>>(boxes, area, valid, mask);
    nmsreduce_k<<<1, 256, 0, stream>>>(mask, valid, keepw);
    out_k<<<1, 256, 0, stream>>>(keepw, boxes, out_roi);
    anchors_k<<<576, 256, 0, stream>>>(out_anch);
}

// Round 16
// 3461.987 us; speedup vs baseline: 1.6004x; 1.0775x over previous
//
#include <hip/hip_runtime.h>
#include <math.h>

// ---------------------------------------------------------------------------
// RPN pipeline — PASSING semantics (R14): f64 conv -> h stored f32 -> f64
// head -> logits stored f32 -> f64 softmax -> f64 fg ordering. Faithful-f32
// box/NMS. R16: conv3_k v2 (4x2px x 4oc/thread, f64 LDS staging, padded
// stride — LDS-pipe fix) + ranksort_k re-gridded 256x64. Accumulation order
// per output is UNCHANGED (cb -> cc -> tap) — bit-identical numerics.
// Outputs (f32, concatenated):
//   [0]        rpn_locs   147456 x 4
//   [589824]   rpn_scores 147456 x 2
//   [884736]   roi_out      2000 x 4
//   [892736]   anchors    147456 x 4
// ---------------------------------------------------------------------------

#define NPX    16384
#define NANCH  147456
#define NSEL   12000
#define NW     188
#define NPOST  2000
#define MCAP   16384

static const size_t WS_HT    = 0;                      // f32 h: 16384*512*4 = 33554432
static const size_t WS_MASK  = 0;                      // overlays HT after head_k (18MB)
static const size_t WS_KEY   = 33554432;               // 147456*4
static const size_t WS_WT    = WS_KEY  + 589824;       // f32 512*64*4 = 131072
static const size_t WS_FGD   = WS_WT   + 131072;       // f64 147456*8 = 1179648
static const size_t WS_ZERO0 = WS_FGD  + 1179648;      // ---- zeroed ----
static const size_t WS_HIST1 = WS_ZERO0;               // 262144
static const size_t WS_HIST2 = WS_HIST1 + 262144;      // 262144
static const size_t WS_CTRL  = WS_HIST2 + 262144;      // 256
static const size_t WS_ZEND  = WS_CTRL  + 256;         // ---- end zeroed ----
static const size_t WS_SELI  = WS_ZEND;                // 65536
static const size_t WS_SELD  = WS_SELI + 65536;        // 131072
static const size_t WS_SORT  = WS_SELD + 131072;       // 48128
static const size_t WS_BOX   = WS_SORT + 48128;        // f32 192256
static const size_t WS_AREA  = WS_BOX  + 192256;       // 48128
static const size_t WS_VALID = WS_AREA + 48128;        // 48128
static const size_t WS_KEEP  = WS_VALID + 48128;       // 1536

// ---------------------------------------------------------------------------
// 3x3 conv 512->512, SAME, fp64 accumulation (order: cb -> cc -> taps),
// bias + leaky in f64, CAST TO F32. v2 geometry:
//   block 256 thr = 8 oc-groups (4 oc each) x 32 px-slots (4y x 2x px each)
//   block tile = 16x16 px x 32 oc; grid (64, 16).
//   LDS: x staged as f64 (stride 22 to break sy-conflicts), weights f64.
// ---------------------------------------------------------------------------
__global__ __launch_bounds__(256) void conv3_k(const float* __restrict__ x,
                                               const float* __restrict__ w,
                                               const float* __restrict__ bias,
                                               float* __restrict__ ht)
{
    __shared__ double xsd[8][18][22];
    __shared__ double wsm[8][32][10];
    const int tid = threadIdx.x;
    const int og  = tid >> 5;           // 0..7 (oc group of 4)
    const int s   = tid & 31;
    const int sy  = s >> 3, sx = s & 7; // 4x8 grid of (4y x 2x) px sub-tiles
    const int bx  = blockIdx.x;
    const int ocb = blockIdx.y * 32;
    const int py0 = (bx >> 3) * 16;
    const int px0 = (bx & 7) * 16;
    const int ry0 = sy * 4;
    const int cx0 = sx * 2;

    double acc[4][2][4];
#pragma unroll
    for (int iy = 0; iy < 4; iy++)
#pragma unroll
        for (int ix = 0; ix < 2; ix++)
#pragma unroll
            for (int o = 0; o < 4; o++) acc[iy][ix][o] = 0.0;

    const int ocw = tid & 31, ccw = tid >> 5;

    for (int cb = 0; cb < 512; cb += 8) {
        // stage x halo tile as f64 (18x18 per channel)
        for (int t = tid; t < 8 * 18 * 18; t += 256) {
            int cc = t / 324; int rem = t - cc * 324;
            int row = rem / 18; int col = rem - row * 18;
            int gy = py0 - 1 + row, gx = px0 - 1 + col;
            double v = 0.0;
            if ((unsigned)gy < 128u && (unsigned)gx < 128u)
                v = (double)x[(size_t)(cb + cc) * 16384 + gy * 128 + gx];
            xsd[cc][row][col] = v;
        }
        // stage weights as f64: 8 cc x 32 oc x 9
        {
            const float* wp = w + ((size_t)(ocb + ocw) * 512 + (cb + ccw)) * 9;
#pragma unroll
            for (int k = 0; k < 9; k++) wsm[ccw][ocw][k] = (double)wp[k];
        }
        __syncthreads();
#pragma unroll
        for (int cc = 0; cc < 8; ++cc) {
            double xv[6][4];
#pragma unroll
            for (int r = 0; r < 6; r++) {
                const double2* xp = (const double2*)&xsd[cc][ry0 + r][cx0];
                double2 a = xp[0], b = xp[1];
                xv[r][0] = a.x; xv[r][1] = a.y; xv[r][2] = b.x; xv[r][3] = b.y;
            }
#pragma unroll
            for (int o = 0; o < 4; o++) {
                const double* wr = &wsm[cc][og * 4 + o][0];
                double wk[9];
#pragma unroll
                for (int k = 0; k < 9; k++) wk[k] = wr[k];
#pragma unroll
                for (int iy = 0; iy < 4; iy++)
#pragma unroll
                    for (int ix = 0; ix < 2; ix++) {
                        double ss = acc[iy][ix][o];
                        ss = fma(xv[iy + 0][ix + 0], wk[0], ss);
                        ss = fma(xv[iy + 0][ix + 1], wk[1], ss);
                        ss = fma(xv[iy + 0][ix + 2], wk[2], ss);
                        ss = fma(xv[iy + 1][ix + 0], wk[3], ss);
                        ss = fma(xv[iy + 1][ix + 1], wk[4], ss);
                        ss = fma(xv[iy + 1][ix + 2], wk[5], ss);
                        ss = fma(xv[iy + 2][ix + 0], wk[6], ss);
                        ss = fma(xv[iy + 2][ix + 1], wk[7], ss);
                        ss = fma(xv[iy + 2][ix + 2], wk[8], ss);
                        acc[iy][ix][o] = ss;
                    }
            }
        }
        __syncthreads();
    }
    double bv[4];
#pragma unroll
    for (int o = 0; o < 4; o++) bv[o] = (double)bias[ocb + og * 4 + o];
#pragma unroll
    for (int iy = 0; iy < 4; iy++)
#pragma unroll
        for (int ix = 0; ix < 2; ix++) {
            int y = py0 + ry0 + iy, xx = px0 + cx0 + ix;
            size_t p = (size_t)y * 128 + xx;
            float o0[4];
#pragma unroll
            for (int o = 0; o < 4; o++) {
                double v = acc[iy][ix][o] + bv[o];
                double lv = (v >= 0.0) ? v : 0.01 * v;
                o0[o] = (float)lv;                    // h materialized f32
            }
            float4* dst = (float4*)(ht + p * 512 + ocb + og * 4);
            dst[0] = make_float4(o0[0], o0[1], o0[2], o0[3]);
        }
}

__global__ __launch_bounds__(256) void wt_build_k(const float* __restrict__ lw,
                                                  const float* __restrict__ sw,
                                                  float* __restrict__ wT)
{
    int i = blockIdx.x * 256 + threadIdx.x;
    if (i >= 512 * 64) return;
    int c = i >> 6, k = i & 63;
    float v = 0.f;
    if (k < 36) v = lw[(size_t)k * 512 + c];
    else if (k < 54) v = sw[(size_t)(k - 36) * 512 + c];
    wT[(size_t)c * 64 + k] = v;
}

// 1x1 heads: f64 accumulation over f32 h; LOGITS cast to f32; f64 softmax
// on upcast logits; f64 fg + f32 key out.
__global__ __launch_bounds__(256) void head_k(const float* __restrict__ ht,
                                              const float* __restrict__ wT,
                                              const float* __restrict__ locb,
                                              const float* __restrict__ scoreb,
                                              float* __restrict__ out_locs,
                                              float* __restrict__ out_scores,
                                              double* __restrict__ fgd,
                                              unsigned* __restrict__ key)
{
    __shared__ float hrow[4][512];
    const int tid = threadIdx.x;
    const int lw = tid >> 6, lane = tid & 63;
    for (int it = 0; it < 2; ++it) {
        int p = (blockIdx.x * 4 + lw) * 2 + it;
        const float4* hp = (const float4*)(ht + (size_t)p * 512);
        float4 v0 = hp[lane];
        float4 v1 = hp[lane + 64];
        ((float4*)hrow[lw])[lane] = v0;
        ((float4*)hrow[lw])[lane + 64] = v1;
        __syncthreads();
        double acc = 0.0;
        const float* hr = hrow[lw];
        for (int c4 = 0; c4 < 128; c4++) {
            float4 h4 = ((const float4*)hr)[c4];
            float w0 = wT[(size_t)(c4 * 4 + 0) * 64 + lane];
            float w1 = wT[(size_t)(c4 * 4 + 1) * 64 + lane];
            float w2 = wT[(size_t)(c4 * 4 + 2) * 64 + lane];
            float w3 = wT[(size_t)(c4 * 4 + 3) * 64 + lane];
            acc = fma((double)h4.x, (double)w0, acc);
            acc = fma((double)h4.y, (double)w1, acc);
            acc = fma((double)h4.z, (double)w2, acc);
            acc = fma((double)h4.w, (double)w3, acc);
        }
        if (lane < 36) {
            out_locs[(size_t)p * 36 + lane] = (float)(acc + (double)locb[lane]);
        } else if (lane < 54) {
            int ch = lane - 36;
            float svf = (float)(acc + (double)scoreb[ch]);  // logits stored f32
            double sv = (double)svf;                        // softmax upcast f64
            double ov = __shfl(sv, lane ^ 1);
            double s0 = (ch & 1) ? ov : sv;
            double s1 = (ch & 1) ? sv : ov;
            double m = fmax(s0, s1);
            double e0 = exp(s0 - m), e1 = exp(s1 - m);
            double den = e0 + e1;
            double my = ((ch & 1) ? e1 : e0) / den;         // fg stays f64
            out_scores[(size_t)p * 18 + ch] = (float)my;
            if (ch & 1) {
                fgd[(size_t)p * 9 + (ch >> 1)] = my;
                key[(size_t)p * 9 + (ch >> 1)] = __float_as_uint((float)my);
            }
        }
        __syncthreads();
    }
}

__global__ __launch_bounds__(256) void hist1_k(const unsigned* __restrict__ key,
                                               unsigned* __restrict__ hist)
{
    int i = blockIdx.x * 256 + threadIdx.x;
    if (i < NANCH) atomicAdd(&hist[key[i] >> 16], 1u);
}

__global__ __launch_bounds__(256) void hist2_k(const unsigned* __restrict__ key,
                                               const unsigned* __restrict__ ctrl,
                                               unsigned* __restrict__ hist)
{
    int i = blockIdx.x * 256 + threadIdx.x;
    if (i < NANCH) {
        unsigned k = key[i];
        if ((k >> 16) == ctrl[2]) atomicAdd(&hist[k & 0xffffu], 1u);
    }
}

__global__ __launch_bounds__(256) void scan_k(const unsigned* __restrict__ hist,
                                              unsigned* __restrict__ ctrl, int mode)
{
    __shared__ unsigned csum[256];
    __shared__ unsigned binv[256];
    __shared__ int sChunk;
    __shared__ unsigned sAcc;
    int tid = threadIdx.x;
    unsigned base = (mode == 0) ? 0u : ctrl[3];
    unsigned s = 0;
    for (int b = 0; b < 256; ++b) s += hist[tid * 256 + b];
    csum[tid] = s;
    __syncthreads();
    if (tid == 0) {
        unsigned acc = base; int c = 0;
        for (int t = 255; t >= 0; --t) {
            if (acc + csum[t] >= (unsigned)NSEL) { c = t; break; }
            acc += csum[t];
        }
        sChunk = c; sAcc = acc;
    }
    __syncthreads();
    int c = sChunk;
    binv[tid] = hist[c * 256 + tid];
    __syncthreads();
    if (tid == 0) {
        unsigned acc = sAcc; int bsel = 0;
        for (int t = 255; t >= 0; --t) {
            if (acc + binv[t] >= (unsigned)NSEL) { bsel = t; break; }
            acc += binv[t];
        }
        unsigned binidx = (unsigned)(c * 256 + bsel);
        if (mode == 0) { ctrl[2] = binidx; ctrl[3] = acc; }
        else           { ctrl[4] = (ctrl[2] << 16) | binidx; }
    }
}

__global__ __launch_bounds__(256) void compact_k(const unsigned* __restrict__ key,
                                                 const double* __restrict__ fgd,
                                                 unsigned* __restrict__ ctrl,
                                                 unsigned* __restrict__ seli,
                                                 double* __restrict__ seld)
{
    int i = blockIdx.x * 256 + threadIdx.x;
    if (i >= NANCH) return;
    unsigned k = key[i], T = ctrl[4];
    if (k >= T) {
        unsigned pos = atomicAdd(&ctrl[0], 1u);
        if (pos < (unsigned)MCAP) { seli[pos] = (unsigned)i; seld[pos] = fgd[i]; }
    }
}

// exact rank among candidates by (f64 fg desc, idx asc) — 256 blocks x 64 thr
__global__ __launch_bounds__(64) void ranksort_k(const unsigned* __restrict__ ctrl,
                                                 const unsigned* __restrict__ seli,
                                                 const double* __restrict__ seld,
                                                 unsigned* __restrict__ sorted)
{
    __shared__ double  sd[1024];
    __shared__ unsigned si[1024];
    int i = blockIdx.x * 64 + threadIdx.x;   // 0..16383
    unsigned M = ctrl[0]; if (M > (unsigned)MCAP) M = (unsigned)MCAP;
    double di = 0.0; unsigned ii = 0xFFFFFFFFu;
    if (i < (int)M) { di = seld[i]; ii = seli[i]; }
    unsigned r = 0;
    for (unsigned t0 = 0; t0 < M; t0 += 1024) {
        unsigned tn = (M - t0 < 1024u) ? (M - t0) : 1024u;
        __syncthreads();
        for (unsigned t = threadIdx.x; t < tn; t += 64) { sd[t] = seld[t0 + t]; si[t] = seli[t0 + t]; }
        __syncthreads();
        if (i < (int)M) {
            if (tn == 1024u) {
#pragma unroll 8
                for (unsigned t = 0; t < 1024u; ++t) {
                    double dj = sd[t];
                    r += (dj > di || (dj == di && si[t] < ii)) ? 1u : 0u;
                }
            } else {
                for (unsigned t = 0; t < tn; ++t) {
                    double dj = sd[t];
                    r += (dj > di || (dj == di && si[t] < ii)) ? 1u : 0u;
                }
            }
        }
    }
    if (i < (int)M && r < (unsigned)NSEL) sorted[r] = ii;
}

// faithful-f32 box path (proven insensitive)
__global__ __launch_bounds__(256) void box_k(const unsigned* __restrict__ sorted,
                                             const float* __restrict__ locs,
                                             const int* __restrict__ img_h,
                                             const int* __restrict__ img_w,
                                             float* __restrict__ boxes,
                                             float* __restrict__ area,
                                             unsigned* __restrict__ valid)
{
    int i = blockIdx.x * 256 + threadIdx.x;
    if (i >= NSEL) return;
    unsigned src = sorted[i];
    int a = src % 9; int p = src / 9; int gx = p & 127; int gy = p >> 7;
    int ri = a / 3, si = a - ri * 3;
    double rr = (ri == 0) ? 0.5 : ((ri == 1) ? 1.0 : 2.0);
    double ss = (si == 0) ? 8.0 : ((si == 1) ? 16.0 : 32.0);
    double bh = 16.0 * ss * sqrt(rr);
    double bw = 16.0 * ss * sqrt(1.0 / rr);
    float b0 = (float)(-bh / 2.0), b1 = (float)(-bw / 2.0);
    float b2 = (float)(bh / 2.0),  b3 = (float)(bw / 2.0);
    float cy = (float)(gy * 16 + 8), cx = (float)(gx * 16 + 8);
    float a0 = __fadd_rn(cy, b0), a1 = __fadd_rn(cx, b1);
    float a2 = __fadd_rn(cy, b2), a3 = __fadd_rn(cx, b3);
    float ah = __fsub_rn(a2, a0), aw = __fsub_rn(a3, a1);
    float acy = __fadd_rn(a0, __fmul_rn(0.5f, ah));
    float acx = __fadd_rn(a1, __fmul_rn(0.5f, aw));
    const float* lp = locs + (size_t)src * 4;
    float dy = lp[0], dx = lp[1], dh = lp[2], dw = lp[3];
    float ncy = __fadd_rn(__fmul_rn(dy, ah), acy);
    float ncx = __fadd_rn(__fmul_rn(dx, aw), acx);
    float edh = (float)exp((double)dh);
    float edw = (float)exp((double)dw);
    float hh  = __fmul_rn(ah, edh);
    float wwv = __fmul_rn(aw, edw);
    float y1 = __fsub_rn(ncy, __fmul_rn(0.5f, hh));
    float x1 = __fsub_rn(ncx, __fmul_rn(0.5f, wwv));
    float y2 = __fadd_rn(ncy, __fmul_rn(0.5f, hh));
    float x2 = __fadd_rn(ncx, __fmul_rn(0.5f, wwv));
    float ihf = (float)img_h[0], iwf = (float)img_w[0];
    y1 = fminf(fmaxf(y1, 0.f), ihf);
    x1 = fminf(fmaxf(x1, 0.f), iwf);
    y2 = fminf(fmaxf(y2, 0.f), ihf);
    x2 = fminf(fmaxf(x2, 0.f), iwf);
    float dyv = __fsub_rn(y2, y1), dxv = __fsub_rn(x2, x1);
    unsigned v = (dyv >= 16.f && dxv >= 16.f) ? 1u : 0u;
    boxes[(size_t)i * 4 + 0] = y1;
    boxes[(size_t)i * 4 + 1] = x1;
    boxes[(size_t)i * 4 + 2] = y2;
    boxes[(size_t)i * 4 + 3] = x2;
    area[i] = __fmul_rn(dyv, dxv);
    valid[i] = v;
}

__global__ __launch_bounds__(64) void mask_k(const float* __restrict__ boxes,
                                             const float* __restrict__ area,
                                             const unsigned* __restrict__ valid,
                                             unsigned long long* __restrict__ mask)
{
    int gyb = blockIdx.y, gxb = blockIdx.x;
    if (gxb < gyb) return;
    __shared__ float bj[64][4];
    __shared__ float aj[64];
    int t = threadIdx.x;
    int j = gxb * 64 + t;
    if (j < NSEL) {
        bj[t][0] = boxes[(size_t)j * 4 + 0];
        bj[t][1] = boxes[(size_t)j * 4 + 1];
        bj[t][2] = boxes[(size_t)j * 4 + 2];
        bj[t][3] = boxes[(size_t)j * 4 + 3];
        aj[t] = area[j];
    }
    __syncthreads();
    int r = gyb * 64 + t;
    if (r >= NSEL) return;
    unsigned long long wbits = 0ull;
    if (valid[r]) {
        float ry1 = boxes[(size_t)r * 4 + 0], rx1 = boxes[(size_t)r * 4 + 1];
        float ry2 = boxes[(size_t)r * 4 + 2], rx2 = boxes[(size_t)r * 4 + 3];
        float ra = area[r];
        int jmax = min(64, NSEL - gxb * 64);
        for (int jj = 0; jj < jmax; ++jj) {
            int jidx = gxb * 64 + jj;
            if (jidx <= r) continue;
            float yy1 = fmaxf(ry1, bj[jj][0]);
            float xx1 = fmaxf(rx1, bj[jj][1]);
            float yy2 = fminf(ry2, bj[jj][2]);
            float xx2 = fminf(rx2, bj[jj][3]);
            float ihh = fmaxf(__fsub_rn(yy2, yy1), 0.f);
            float iww = fmaxf(__fsub_rn(xx2, xx1), 0.f);
            float inter = __fmul_rn(ihh, iww);
            float denom = __fadd_rn(__fsub_rn(__fadd_rn(ra, aj[jj]), inter), 1e-10f);
            float iou = inter / denom;
            if (iou > 0.7f) wbits |= (1ull << jj);
        }
    }
    mask[(size_t)r * NW + gxb] = wbits;
}

// Greedy NMS reduce — alive-list propagate + early break (output-invariant)
__global__ __launch_bounds__(256) void nmsreduce_k(const unsigned long long* __restrict__ mask,
                                                   const unsigned* __restrict__ valid,
                                                   unsigned long long* __restrict__ keepw)
{
    __shared__ unsigned long long supp[NW];
    __shared__ unsigned long long validw[NW];
    __shared__ unsigned long long dmS[64];
    __shared__ unsigned char aliveL[64];
    __shared__ int aliveC;
    __shared__ int keptTot;
    int tid = threadIdx.x;
    for (int g = tid; g < NW; g += 256) {
        unsigned long long w = 0ull;
        int r0 = g * 64, lim = min(64, NSEL - r0);
        for (int b = 0; b < lim; ++b)
            if (valid[r0 + b]) w |= (1ull << b);
        validw[g] = w; supp[g] = 0ull;
    }
    if (tid == 0) keptTot = 0;
    __syncthreads();
    for (int g = 0; g < NW; ++g) {
        if (tid < 64) {
            int r = g * 64 + tid;
            dmS[tid] = (r < NSEL) ? mask[(size_t)r * NW + g] : 0ull;
        }
        __syncthreads();
        if (tid < 64) {
            unsigned long long m = dmS[tid];
            unsigned long long w = supp[g];
            unsigned long long cand = ~w;
            while (cand) {
                int b = __ffsll((unsigned long long)cand) - 1;
                unsigned long long vb = __shfl(m, b);
                w |= vb;
                cand = (b >= 63) ? 0ull : (~w & (~0ull << (b + 1)));
            }
            if (tid == 0) {
                supp[g] = w;
                unsigned long long alive = ~w & validw[g];
                keepw[g] = alive;
                int c = 0;
                unsigned long long aa = alive;
                while (aa) {
                    int b = __ffsll((unsigned long long)aa) - 1;
                    aa &= aa - 1;
                    aliveL[c++] = (unsigned char)b;
                }
                aliveC = c;
                keptTot += c;
            }
        }
        __syncthreads();
        if (keptTot >= NPOST) {
            for (int g2 = g + 1 + tid; g2 < NW; g2 += 256) keepw[g2] = 0ull;
            break;
        }
        int cnt = aliveC;
        if (cnt > 0) {
            const unsigned long long* mrow0 = mask + (size_t)g * 64 * NW;
            for (int g2 = g + 1 + tid; g2 < NW; g2 += 256) {
                unsigned long long acc = supp[g2];
#pragma unroll 4
                for (int bi = 0; bi < cnt; ++bi)
                    acc |= mrow0[(size_t)aliveL[bi] * NW + g2];
                supp[g2] = acc;
            }
        }
        __syncthreads();
    }
}

__global__ __launch_bounds__(256) void out_k(const unsigned long long* __restrict__ keepw,
                                             const float* __restrict__ boxes,
                                             float* __restrict__ out2)
{
    __shared__ unsigned pref[NW + 1];
    int tid = threadIdx.x;
    for (int t = tid; t < NPOST * 4; t += 256) out2[t] = 0.f;
    __syncthreads();
    if (tid == 0) {
        unsigned acc = 0;
        for (int g = 0; g < NW; ++g) { pref[g] = acc; acc += __popcll(keepw[g]); }
        pref[NW] = acc;
    }
    __syncthreads();
    for (int r = tid; r < NSEL; r += 256) {
        int g = r >> 6, b = r & 63;
        unsigned long long w = keepw[g];
        if ((w >> b) & 1ull) {
            unsigned rk = pref[g] + (unsigned)__popcll(w & ((1ull << b) - 1ull));
            if (rk < NPOST) {
                out2[(size_t)rk * 4 + 0] = boxes[(size_t)r * 4 + 0];
                out2[(size_t)rk * 4 + 1] = boxes[(size_t)r * 4 + 1];
                out2[(size_t)rk * 4 + 2] = boxes[(size_t)r * 4 + 2];
                out2[(size_t)rk * 4 + 3] = boxes[(size_t)r * 4 + 3];
            }
        }
    }
}

__global__ __launch_bounds__(256) void anchors_k(float* __restrict__ out3)
{
    int i = blockIdx.x * 256 + threadIdx.x;
    if (i >= NANCH) return;
    int a = i % 9; int p = i / 9; int gx = p & 127, gy = p >> 7;
    int ri = a / 3, si = a - ri * 3;
    double rr = (ri == 0) ? 0.5 : ((ri == 1) ? 1.0 : 2.0);
    double ss = (si == 0) ? 8.0 : ((si == 1) ? 16.0 : 32.0);
    double bh = 16.0 * ss * sqrt(rr);
    double bw = 16.0 * ss * sqrt(1.0 / rr);
    float b0 = (float)(-bh / 2.0), b1 = (float)(-bw / 2.0);
    float b2 = (float)(bh / 2.0),  b3 = (float)(bw / 2.0);
    float cy = (float)(gy * 16 + 8), cx = (float)(gx * 16 + 8);
    out3[(size_t)i * 4 + 0] = cy + b0;
    out3[(size_t)i * 4 + 1] = cx + b1;
    out3[(size_t)i * 4 + 2] = cy + b2;
    out3[(size_t)i * 4 + 3] = cx + b3;
}

extern "C" void kernel_launch(void* const* d_in, const int* in_sizes, int n_in,
                              void* d_out, int out_size, void* d_ws, size_t ws_size,
                              hipStream_t stream)
{
    const float* x       = (const float*)d_in[0];
    const float* conv_w  = (const float*)d_in[1];
    const float* conv_b  = (const float*)d_in[2];
    const float* score_w = (const float*)d_in[3];
    const float* score_b = (const float*)d_in[4];
    const float* loc_w   = (const float*)d_in[5];
    const float* loc_b   = (const float*)d_in[6];
    const int*   img_h   = (const int*)d_in[7];
    const int*   img_w   = (const int*)d_in[8];

    float* out        = (float*)d_out;
    float* out_locs   = out;
    float* out_scores = out + 589824;
    float* out_roi    = out + 884736;
    float* out_anch   = out + 892736;

    char* ws = (char*)d_ws;
    float*    ht     = (float*)(ws + WS_HT);
    unsigned* key    = (unsigned*)(ws + WS_KEY);
    float*    wT     = (float*)(ws + WS_WT);
    double*   fgd    = (double*)(ws + WS_FGD);
    unsigned* hist1  = (unsigned*)(ws + WS_HIST1);
    unsigned* hist2  = (unsigned*)(ws + WS_HIST2);
    unsigned* ctrl   = (unsigned*)(ws + WS_CTRL);
    unsigned* seli   = (unsigned*)(ws + WS_SELI);
    double*   seld   = (double*)(ws + WS_SELD);
    unsigned* sorted = (unsigned*)(ws + WS_SORT);
    float*    boxes  = (float*)(ws + WS_BOX);
    float*    area   = (float*)(ws + WS_AREA);
    unsigned* valid  = (unsigned*)(ws + WS_VALID);
    unsigned long long* keepw = (unsigned long long*)(ws + WS_KEEP);
    unsigned long long* mask  = (unsigned long long*)(ws + WS_MASK);  // overlays HT

    hipMemsetAsync(ws + WS_ZERO0, 0, WS_ZEND - WS_ZERO0, stream);

    conv3_k<<<dim3(64, 16), 256, 0, stream>>>(x, conv_w, conv_b, ht);
    wt_build_k<<<128, 256, 0, stream>>>(loc_w, score_w, wT);
    head_k<<<2048, 256, 0, stream>>>(ht, wT, loc_b, score_b, out_locs, out_scores, fgd, key);
    hist1_k<<<576, 256, 0, stream>>>(key, hist1);
    scan_k<<<1, 256, 0, stream>>>(hist1, ctrl, 0);
    hist2_k<<<576, 256, 0, stream>>>(key, ctrl, hist2);
    scan_k<<<1, 256, 0, stream>>>(hist2, ctrl, 1);
    compact_k<<<576, 256, 0, stream>>>(key, fgd, ctrl, seli, seld);
    ranksort_k<<<256, 64, 0, stream>>>(ctrl, seli, seld, sorted);
    box_k<<<47, 256, 0, stream>>>(sorted, out_locs, img_h, img_w, boxes, area, valid);
    mask_k<<<dim3(NW, NW), 64, 0, stream>>>(boxes, area, valid, mask);
    nmsreduce_k<<<1, 256, 0, stream>>>(mask, valid, keepw);
    out_k<<<1, 256, 0, stream>>>(keepw, boxes, out_roi);
    anchors_k<<<576, 256, 0, stream>>>(out_anch);
}

// Round 17
// 2412.136 us; speedup vs baseline: 2.2970x; 1.4352x over previous
//
#include <hip/hip_runtime.h>
#include <math.h>

// ---------------------------------------------------------------------------
// RPN pipeline — PASSING semantics (R14): f64 conv -> h stored f32 -> f64
// head -> logits stored f32 -> f64 softmax -> f64 fg ordering. Faithful-f32
// box/NMS. R17: conv3_k v3 (f32 x-staging stride-22, f64 weights, register
// prefetch of next K-step = T14 async-STAGE) — accumulation order unchanged,
// bit-identical numerics. ranksort -> rankpart(64x16, atomic partial sums) +
// scatter (order-independent).
// Outputs (f32, concatenated):
//   [0]        rpn_locs   147456 x 4
//   [589824]   rpn_scores 147456 x 2
//   [884736]   roi_out      2000 x 4
//   [892736]   anchors    147456 x 4
// ---------------------------------------------------------------------------

#define NPX    16384
#define NANCH  147456
#define NSEL   12000
#define NW     188
#define NPOST  2000
#define MCAP   16384

static const size_t WS_HT    = 0;                      // f32 h: 33554432
static const size_t WS_MASK  = 0;                      // overlays HT after head_k
static const size_t WS_KEY   = 33554432;               // 147456*4
static const size_t WS_WT    = WS_KEY  + 589824;       // 131072
static const size_t WS_FGD   = WS_WT   + 131072;       // 1179648
static const size_t WS_ZERO0 = WS_FGD  + 1179648;      // ---- zeroed ----
static const size_t WS_HIST1 = WS_ZERO0;               // 262144
static const size_t WS_HIST2 = WS_HIST1 + 262144;      // 262144
static const size_t WS_RANK  = WS_HIST2 + 262144;      // 65536
static const size_t WS_CTRL  = WS_RANK  + 65536;       // 256
static const size_t WS_ZEND  = WS_CTRL  + 256;         // ---- end zeroed ----
static const size_t WS_SELI  = WS_ZEND;                // 65536
static const size_t WS_SELD  = WS_SELI + 65536;        // 131072
static const size_t WS_SORT  = WS_SELD + 131072;       // 48128
static const size_t WS_BOX   = WS_SORT + 48128;        // 192256
static const size_t WS_AREA  = WS_BOX  + 192256;       // 48128
static const size_t WS_VALID = WS_AREA + 48128;        // 48128
static const size_t WS_KEEP  = WS_VALID + 48128;       // 1536

// ---------------------------------------------------------------------------
// 3x3 conv 512->512, SAME, fp64 accumulation (order: cb -> cc -> o -> px -> tap),
// bias + leaky in f64, CAST TO F32. v3:
//   block 256 thr = 8 oc-groups (4 oc) x 32 px-slots (4y x 2x); tile 16x16x32.
//   LDS: x f32 [8][18][22]; w f64 [8][32][9]. Register prefetch of next step.
// ---------------------------------------------------------------------------
__global__ __launch_bounds__(256) void conv3_k(const float* __restrict__ x,
                                               const float* __restrict__ w,
                                               const float* __restrict__ bias,
                                               float* __restrict__ ht)
{
    __shared__ float  xsf[8][18][22];
    __shared__ double wsm[8][32][9];
    const int tid = threadIdx.x;
    const int og  = tid >> 5;           // 0..7 (oc group of 4)
    const int s   = tid & 31;
    const int sy  = s >> 3, sx = s & 7;
    const int bx  = blockIdx.x;
    const int ocb = blockIdx.y * 32;
    const int py0 = (bx >> 3) * 16;
    const int px0 = (bx & 7) * 16;
    const int ry0 = sy * 4;
    const int cx0 = sx * 2;

    double acc[4][2][4];
#pragma unroll
    for (int iy = 0; iy < 4; iy++)
#pragma unroll
        for (int ix = 0; ix < 2; ix++)
#pragma unroll
            for (int o = 0; o < 4; o++) acc[iy][ix][o] = 0.0;

    // precomputed staging descriptors (constant across cb steps)
    int goff[11];    // global offset within channel-plane stack (-1 => zero)
    int widx[11];    // LDS float index
#pragma unroll
    for (int k = 0; k < 11; k++) {
        int t = tid + k * 256;
        if (t < 2592) {
            int cc = t / 324; int rem = t - cc * 324;
            int row = rem / 18; int col = rem - row * 18;
            int gy = py0 - 1 + row, gx = px0 - 1 + col;
            widx[k] = cc * (18 * 22) + row * 22 + col;
            goff[k] = ((unsigned)gy < 128u && (unsigned)gx < 128u)
                      ? (cc * 16384 + gy * 128 + gx) : -1;
        } else { widx[k] = -1; goff[k] = -1; }
    }
    const int ocw = tid & 31, ccw = tid >> 5;
    const float* wbase = w + ((size_t)(ocb + ocw) * 512 + ccw) * 9;

    float pxr[11];
    float pwr[9];

    // prologue: stage step 0
#pragma unroll
    for (int k = 0; k < 11; k++)
        pxr[k] = (goff[k] >= 0) ? x[goff[k]] : 0.f;
    {
        const float* wp = wbase;
#pragma unroll
        for (int k = 0; k < 9; k++) pwr[k] = wp[k];
    }
#pragma unroll
    for (int k = 0; k < 11; k++)
        if (widx[k] >= 0) ((float*)xsf)[widx[k]] = pxr[k];
#pragma unroll
    for (int k = 0; k < 9; k++) wsm[ccw][ocw][k] = (double)pwr[k];
    __syncthreads();

    for (int cb = 0; cb < 512; cb += 8) {
        const bool more = (cb + 8) < 512;
        if (more) {
            const float* xb = x + (size_t)(cb + 8) * 16384;
#pragma unroll
            for (int k = 0; k < 11; k++)
                pxr[k] = (goff[k] >= 0) ? xb[goff[k]] : 0.f;
            const float* wp = wbase + (size_t)(cb + 8) * 9;
#pragma unroll
            for (int k = 0; k < 9; k++) pwr[k] = wp[k];
        }
        // compute current step
#pragma unroll
        for (int cc = 0; cc < 8; ++cc) {
            double xv[6][4];
#pragma unroll
            for (int r = 0; r < 6; r++) {
                const float2* xp = (const float2*)&xsf[cc][ry0 + r][cx0];
                float2 a = xp[0], b = xp[1];
                xv[r][0] = (double)a.x; xv[r][1] = (double)a.y;
                xv[r][2] = (double)b.x; xv[r][3] = (double)b.y;
            }
#pragma unroll
            for (int o = 0; o < 4; o++) {
                const double* wr = &wsm[cc][og * 4 + o][0];
                double wk[9];
#pragma unroll
                for (int k = 0; k < 9; k++) wk[k] = wr[k];
#pragma unroll
                for (int iy = 0; iy < 4; iy++)
#pragma unroll
                    for (int ix = 0; ix < 2; ix++) {
                        double ss = acc[iy][ix][o];
                        ss = fma(xv[iy + 0][ix + 0], wk[0], ss);
                        ss = fma(xv[iy + 0][ix + 1], wk[1], ss);
                        ss = fma(xv[iy + 0][ix + 2], wk[2], ss);
                        ss = fma(xv[iy + 1][ix + 0], wk[3], ss);
                        ss = fma(xv[iy + 1][ix + 1], wk[4], ss);
                        ss = fma(xv[iy + 1][ix + 2], wk[5], ss);
                        ss = fma(xv[iy + 2][ix + 0], wk[6], ss);
                        ss = fma(xv[iy + 2][ix + 1], wk[7], ss);
                        ss = fma(xv[iy + 2][ix + 2], wk[8], ss);
                        acc[iy][ix][o] = ss;
                    }
            }
        }
        __syncthreads();
        if (more) {
#pragma unroll
            for (int k = 0; k < 11; k++)
                if (widx[k] >= 0) ((float*)xsf)[widx[k]] = pxr[k];
#pragma unroll
            for (int k = 0; k < 9; k++) wsm[ccw][ocw][k] = (double)pwr[k];
            __syncthreads();
        }
    }
    double bv[4];
#pragma unroll
    for (int o = 0; o < 4; o++) bv[o] = (double)bias[ocb + og * 4 + o];
#pragma unroll
    for (int iy = 0; iy < 4; iy++)
#pragma unroll
        for (int ix = 0; ix < 2; ix++) {
            int y = py0 + ry0 + iy, xx = px0 + cx0 + ix;
            size_t p = (size_t)y * 128 + xx;
            float o0[4];
#pragma unroll
            for (int o = 0; o < 4; o++) {
                double v = acc[iy][ix][o] + bv[o];
                double lv = (v >= 0.0) ? v : 0.01 * v;
                o0[o] = (float)lv;                    // h materialized f32
            }
            float4* dst = (float4*)(ht + p * 512 + ocb + og * 4);
            dst[0] = make_float4(o0[0], o0[1], o0[2], o0[3]);
        }
}

__global__ __launch_bounds__(256) void wt_build_k(const float* __restrict__ lw,
                                                  const float* __restrict__ sw,
                                                  float* __restrict__ wT)
{
    int i = blockIdx.x * 256 + threadIdx.x;
    if (i >= 512 * 64) return;
    int c = i >> 6, k = i & 63;
    float v = 0.f;
    if (k < 36) v = lw[(size_t)k * 512 + c];
    else if (k < 54) v = sw[(size_t)(k - 36) * 512 + c];
    wT[(size_t)c * 64 + k] = v;
}

// 1x1 heads: f64 accumulation over f32 h; LOGITS cast to f32; f64 softmax
// on upcast logits; f64 fg + f32 key out.
__global__ __launch_bounds__(256) void head_k(const float* __restrict__ ht,
                                              const float* __restrict__ wT,
                                              const float* __restrict__ locb,
                                              const float* __restrict__ scoreb,
                                              float* __restrict__ out_locs,
                                              float* __restrict__ out_scores,
                                              double* __restrict__ fgd,
                                              unsigned* __restrict__ key)
{
    __shared__ float hrow[4][512];
    const int tid = threadIdx.x;
    const int lw = tid >> 6, lane = tid & 63;
    for (int it = 0; it < 2; ++it) {
        int p = (blockIdx.x * 4 + lw) * 2 + it;
        const float4* hp = (const float4*)(ht + (size_t)p * 512);
        float4 v0 = hp[lane];
        float4 v1 = hp[lane + 64];
        ((float4*)hrow[lw])[lane] = v0;
        ((float4*)hrow[lw])[lane + 64] = v1;
        __syncthreads();
        double acc = 0.0;
        const float* hr = hrow[lw];
        for (int c4 = 0; c4 < 128; c4++) {
            float4 h4 = ((const float4*)hr)[c4];
            float w0 = wT[(size_t)(c4 * 4 + 0) * 64 + lane];
            float w1 = wT[(size_t)(c4 * 4 + 1) * 64 + lane];
            float w2 = wT[(size_t)(c4 * 4 + 2) * 64 + lane];
            float w3 = wT[(size_t)(c4 * 4 + 3) * 64 + lane];
            acc = fma((double)h4.x, (double)w0, acc);
            acc = fma((double)h4.y, (double)w1, acc);
            acc = fma((double)h4.z, (double)w2, acc);
            acc = fma((double)h4.w, (double)w3, acc);
        }
        if (lane < 36) {
            out_locs[(size_t)p * 36 + lane] = (float)(acc + (double)locb[lane]);
        } else if (lane < 54) {
            int ch = lane - 36;
            float svf = (float)(acc + (double)scoreb[ch]);  // logits stored f32
            double sv = (double)svf;                        // softmax upcast f64
            double ov = __shfl(sv, lane ^ 1);
            double s0 = (ch & 1) ? ov : sv;
            double s1 = (ch & 1) ? sv : ov;
            double m = fmax(s0, s1);
            double e0 = exp(s0 - m), e1 = exp(s1 - m);
            double den = e0 + e1;
            double my = ((ch & 1) ? e1 : e0) / den;         // fg stays f64
            out_scores[(size_t)p * 18 + ch] = (float)my;
            if (ch & 1) {
                fgd[(size_t)p * 9 + (ch >> 1)] = my;
                key[(size_t)p * 9 + (ch >> 1)] = __float_as_uint((float)my);
            }
        }
        __syncthreads();
    }
}

__global__ __launch_bounds__(256) void hist1_k(const unsigned* __restrict__ key,
                                               unsigned* __restrict__ hist)
{
    int i = blockIdx.x * 256 + threadIdx.x;
    if (i < NANCH) atomicAdd(&hist[key[i] >> 16], 1u);
}

__global__ __launch_bounds__(256) void hist2_k(const unsigned* __restrict__ key,
                                               const unsigned* __restrict__ ctrl,
                                               unsigned* __restrict__ hist)
{
    int i = blockIdx.x * 256 + threadIdx.x;
    if (i < NANCH) {
        unsigned k = key[i];
        if ((k >> 16) == ctrl[2]) atomicAdd(&hist[k & 0xffffu], 1u);
    }
}

__global__ __launch_bounds__(256) void scan_k(const unsigned* __restrict__ hist,
                                              unsigned* __restrict__ ctrl, int mode)
{
    __shared__ unsigned csum[256];
    __shared__ unsigned binv[256];
    __shared__ int sChunk;
    __shared__ unsigned sAcc;
    int tid = threadIdx.x;
    unsigned base = (mode == 0) ? 0u : ctrl[3];
    unsigned s = 0;
    for (int b = 0; b < 256; ++b) s += hist[tid * 256 + b];
    csum[tid] = s;
    __syncthreads();
    if (tid == 0) {
        unsigned acc = base; int c = 0;
        for (int t = 255; t >= 0; --t) {
            if (acc + csum[t] >= (unsigned)NSEL) { c = t; break; }
            acc += csum[t];
        }
        sChunk = c; sAcc = acc;
    }
    __syncthreads();
    int c = sChunk;
    binv[tid] = hist[c * 256 + tid];
    __syncthreads();
    if (tid == 0) {
        unsigned acc = sAcc; int bsel = 0;
        for (int t = 255; t >= 0; --t) {
            if (acc + binv[t] >= (unsigned)NSEL) { bsel = t; break; }
            acc += binv[t];
        }
        unsigned binidx = (unsigned)(c * 256 + bsel);
        if (mode == 0) { ctrl[2] = binidx; ctrl[3] = acc; }
        else           { ctrl[4] = (ctrl[2] << 16) | binidx; }
    }
}

__global__ __launch_bounds__(256) void compact_k(const unsigned* __restrict__ key,
                                                 const double* __restrict__ fgd,
                                                 unsigned* __restrict__ ctrl,
                                                 unsigned* __restrict__ seli,
                                                 double* __restrict__ seld)
{
    int i = blockIdx.x * 256 + threadIdx.x;
    if (i >= NANCH) return;
    unsigned k = key[i], T = ctrl[4];
    if (k >= T) {
        unsigned pos = atomicAdd(&ctrl[0], 1u);
        if (pos < (unsigned)MCAP) { seli[pos] = (unsigned)i; seld[pos] = fgd[i]; }
    }
}

// partial rank by (f64 fg desc, idx asc); grid (64 i-blocks, 16 j-chunks)
__global__ __launch_bounds__(256) void rankpart_k(const unsigned* __restrict__ ctrl,
                                                  const unsigned* __restrict__ seli,
                                                  const double* __restrict__ seld,
                                                  unsigned* __restrict__ rank)
{
    __shared__ double  sd[1024];
    __shared__ unsigned si[1024];
    unsigned M = ctrl[0]; if (M > (unsigned)MCAP) M = (unsigned)MCAP;
    unsigned j0 = blockIdx.y * 1024;
    if (j0 >= M) return;
    unsigned tn = (M - j0 < 1024u) ? (M - j0) : 1024u;
    for (unsigned t = threadIdx.x; t < tn; t += 256) { sd[t] = seld[j0 + t]; si[t] = seli[j0 + t]; }
    __syncthreads();
    int i = blockIdx.x * 256 + threadIdx.x;
    if (i >= (int)M) return;
    double di = seld[i]; unsigned ii = seli[i];
    unsigned r = 0;
    for (unsigned t = 0; t < tn; ++t) {
        double dj = sd[t];
        r += (dj > di || (dj == di && si[t] < ii)) ? 1u : 0u;
    }
    if (r) atomicAdd(&rank[i], r);
}

__global__ __launch_bounds__(256) void scatter2_k(const unsigned* __restrict__ ctrl,
                                                  const unsigned* __restrict__ seli,
                                                  const unsigned* __restrict__ rank,
                                                  unsigned* __restrict__ sorted)
{
    unsigned M = ctrl[0]; if (M > (unsigned)MCAP) M = (unsigned)MCAP;
    int i = blockIdx.x * 256 + threadIdx.x;
    if (i < (int)M) {
        unsigned r = rank[i];
        if (r < (unsigned)NSEL) sorted[r] = seli[i];
    }
}

// faithful-f32 box path (proven insensitive)
__global__ __launch_bounds__(256) void box_k(const unsigned* __restrict__ sorted,
                                             const float* __restrict__ locs,
                                             const int* __restrict__ img_h,
                                             const int* __restrict__ img_w,
                                             float* __restrict__ boxes,
                                             float* __restrict__ area,
                                             unsigned* __restrict__ valid)
{
    int i = blockIdx.x * 256 + threadIdx.x;
    if (i >= NSEL) return;
    unsigned src = sorted[i];
    int a = src % 9; int p = src / 9; int gx = p & 127; int gy = p >> 7;
    int ri = a / 3, si = a - ri * 3;
    double rr = (ri == 0) ? 0.5 : ((ri == 1) ? 1.0 : 2.0);
    double ss = (si == 0) ? 8.0 : ((si == 1) ? 16.0 : 32.0);
    double bh = 16.0 * ss * sqrt(rr);
    double bw = 16.0 * ss * sqrt(1.0 / rr);
    float b0 = (float)(-bh / 2.0), b1 = (float)(-bw / 2.0);
    float b2 = (float)(bh / 2.0),  b3 = (float)(bw / 2.0);
    float cy = (float)(gy * 16 + 8), cx = (float)(gx * 16 + 8);
    float a0 = __fadd_rn(cy, b0), a1 = __fadd_rn(cx, b1);
    float a2 = __fadd_rn(cy, b2), a3 = __fadd_rn(cx, b3);
    float ah = __fsub_rn(a2, a0), aw = __fsub_rn(a3, a1);
    float acy = __fadd_rn(a0, __fmul_rn(0.5f, ah));
    float acx = __fadd_rn(a1, __fmul_rn(0.5f, aw));
    const float* lp = locs + (size_t)src * 4;
    float dy = lp[0], dx = lp[1], dh = lp[2], dw = lp[3];
    float ncy = __fadd_rn(__fmul_rn(dy, ah), acy);
    float ncx = __fadd_rn(__fmul_rn(dx, aw), acx);
    float edh = (float)exp((double)dh);
    float edw = (float)exp((double)dw);
    float hh  = __fmul_rn(ah, edh);
    float wwv = __fmul_rn(aw, edw);
    float y1 = __fsub_rn(ncy, __fmul_rn(0.5f, hh));
    float x1 = __fsub_rn(ncx, __fmul_rn(0.5f, wwv));
    float y2 = __fadd_rn(ncy, __fmul_rn(0.5f, hh));
    float x2 = __fadd_rn(ncx, __fmul_rn(0.5f, wwv));
    float ihf = (float)img_h[0], iwf = (float)img_w[0];
    y1 = fminf(fmaxf(y1, 0.f), ihf);
    x1 = fminf(fmaxf(x1, 0.f), iwf);
    y2 = fminf(fmaxf(y2, 0.f), ihf);
    x2 = fminf(fmaxf(x2, 0.f), iwf);
    float dyv = __fsub_rn(y2, y1), dxv = __fsub_rn(x2, x1);
    unsigned v = (dyv >= 16.f && dxv >= 16.f) ? 1u : 0u;
    boxes[(size_t)i * 4 + 0] = y1;
    boxes[(size_t)i * 4 + 1] = x1;
    boxes[(size_t)i * 4 + 2] = y2;
    boxes[(size_t)i * 4 + 3] = x2;
    area[i] = __fmul_rn(dyv, dxv);
    valid[i] = v;
}

__global__ __launch_bounds__(64) void mask_k(const float* __restrict__ boxes,
                                             const float* __restrict__ area,
                                             const unsigned* __restrict__ valid,
                                             unsigned long long* __restrict__ mask)
{
    int gyb = blockIdx.y, gxb = blockIdx.x;
    if (gxb < gyb) return;
    __shared__ float bj[64][4];
    __shared__ float aj[64];
    int t = threadIdx.x;
    int j = gxb * 64 + t;
    if (j < NSEL) {
        bj[t][0] = boxes[(size_t)j * 4 + 0];
        bj[t][1] = boxes[(size_t)j * 4 + 1];
        bj[t][2] = boxes[(size_t)j * 4 + 2];
        bj[t][3] = boxes[(size_t)j * 4 + 3];
        aj[t] = area[j];
    }
    __syncthreads();
    int r = gyb * 64 + t;
    if (r >= NSEL) return;
    unsigned long long wbits = 0ull;
    if (valid[r]) {
        float ry1 = boxes[(size_t)r * 4 + 0], rx1 = boxes[(size_t)r * 4 + 1];
        float ry2 = boxes[(size_t)r * 4 + 2], rx2 = boxes[(size_t)r * 4 + 3];
        float ra = area[r];
        int jmax = min(64, NSEL - gxb * 64);
        for (int jj = 0; jj < jmax; ++jj) {
            int jidx = gxb * 64 + jj;
            if (jidx <= r) continue;
            float yy1 = fmaxf(ry1, bj[jj][0]);
            float xx1 = fmaxf(rx1, bj[jj][1]);
            float yy2 = fminf(ry2, bj[jj][2]);
            float xx2 = fminf(rx2, bj[jj][3]);
            float ihh = fmaxf(__fsub_rn(yy2, yy1), 0.f);
            float iww = fmaxf(__fsub_rn(xx2, xx1), 0.f);
            float inter = __fmul_rn(ihh, iww);
            float denom = __fadd_rn(__fsub_rn(__fadd_rn(ra, aj[jj]), inter), 1e-10f);
            float iou = inter / denom;
            if (iou > 0.7f) wbits |= (1ull << jj);
        }
    }
    mask[(size_t)r * NW + gxb] = wbits;
}

// Greedy NMS reduce — alive-list propagate + early break (output-invariant)
__global__ __launch_bounds__(256) void nmsreduce_k(const unsigned long long* __restrict__ mask,
                                                   const unsigned* __restrict__ valid,
                                                   unsigned long long* __restrict__ keepw)
{
    __shared__ unsigned long long supp[NW];
    __shared__ unsigned long long validw[NW];
    __shared__ unsigned long long dmS[64];
    __shared__ unsigned char aliveL[64];
    __shared__ int aliveC;
    __shared__ int keptTot;
    int tid = threadIdx.x;
    for (int g = tid; g < NW; g += 256) {
        unsigned long long w = 0ull;
        int r0 = g * 64, lim = min(64, NSEL - r0);
        for (int b = 0; b < lim; ++b)
            if (valid[r0 + b]) w |= (1ull << b);
        validw[g] = w; supp[g] = 0ull;
    }
    if (tid == 0) keptTot = 0;
    __syncthreads();
    for (int g = 0; g < NW; ++g) {
        if (tid < 64) {
            int r = g * 64 + tid;
            dmS[tid] = (r < NSEL) ? mask[(size_t)r * NW + g] : 0ull;
        }
        __syncthreads();
        if (tid < 64) {
            unsigned long long m = dmS[tid];
            unsigned long long w = supp[g];
            unsigned long long cand = ~w;
            while (cand) {
                int b = __ffsll((unsigned long long)cand) - 1;
                unsigned long long vb = __shfl(m, b);
                w |= vb;
                cand = (b >= 63) ? 0ull : (~w & (~0ull << (b + 1)));
            }
            if (tid == 0) {
                supp[g] = w;
                unsigned long long alive = ~w & validw[g];
                keepw[g] = alive;
                int c = 0;
                unsigned long long aa = alive;
                while (aa) {
                    int b = __ffsll((unsigned long long)aa) - 1;
                    aa &= aa - 1;
                    aliveL[c++] = (unsigned char)b;
                }
                aliveC = c;
                keptTot += c;
            }
        }
        __syncthreads();
        if (keptTot >= NPOST) {
            for (int g2 = g + 1 + tid; g2 < NW; g2 += 256) keepw[g2] = 0ull;
            break;
        }
        int cnt = aliveC;
        if (cnt > 0) {
            const unsigned long long* mrow0 = mask + (size_t)g * 64 * NW;
            for (int g2 = g + 1 + tid; g2 < NW; g2 += 256) {
                unsigned long long acc = supp[g2];
#pragma unroll 4
                for (int bi = 0; bi < cnt; ++bi)
                    acc |= mrow0[(size_t)aliveL[bi] * NW + g2];
                supp[g2] = acc;
            }
        }
        __syncthreads();
    }
}

__global__ __launch_bounds__(256) void out_k(const unsigned long long* __restrict__ keepw,
                                             const float* __restrict__ boxes,
                                             float* __restrict__ out2)
{
    __shared__ unsigned pref[NW + 1];
    int tid = threadIdx.x;
    for (int t = tid; t < NPOST * 4; t += 256) out2[t] = 0.f;
    __syncthreads();
    if (tid == 0) {
        unsigned acc = 0;
        for (int g = 0; g < NW; ++g) { pref[g] = acc; acc += __popcll(keepw[g]); }
        pref[NW] = acc;
    }
    __syncthreads();
    for (int r = tid; r < NSEL; r += 256) {
        int g = r >> 6, b = r & 63;
        unsigned long long w = keepw[g];
        if ((w >> b) & 1ull) {
            unsigned rk = pref[g] + (unsigned)__popcll(w & ((1ull << b) - 1ull));
            if (rk < NPOST) {
                out2[(size_t)rk * 4 + 0] = boxes[(size_t)r * 4 + 0];
                out2[(size_t)rk * 4 + 1] = boxes[(size_t)r * 4 + 1];
                out2[(size_t)rk * 4 + 2] = boxes[(size_t)r * 4 + 2];
                out2[(size_t)rk * 4 + 3] = boxes[(size_t)r * 4 + 3];
            }
        }
    }
}

__global__ __launch_bounds__(256) void anchors_k(float* __restrict__ out3)
{
    int i = blockIdx.x * 256 + threadIdx.x;
    if (i >= NANCH) return;
    int a = i % 9; int p = i / 9; int gx = p & 127, gy = p >> 7;
    int ri = a / 3, si = a - ri * 3;
    double rr = (ri == 0) ? 0.5 : ((ri == 1) ? 1.0 : 2.0);
    double ss = (si == 0) ? 8.0 : ((si == 1) ? 16.0 : 32.0);
    double bh = 16.0 * ss * sqrt(rr);
    double bw = 16.0 * ss * sqrt(1.0 / rr);
    float b0 = (float)(-bh / 2.0), b1 = (float)(-bw / 2.0);
    float b2 = (float)(bh / 2.0),  b3 = (float)(bw / 2.0);
    float cy = (float)(gy * 16 + 8), cx = (float)(gx * 16 + 8);
    out3[(size_t)i * 4 + 0] = cy + b0;
    out3[(size_t)i * 4 + 1] = cx + b1;
    out3[(size_t)i * 4 + 2] = cy + b2;
    out3[(size_t)i * 4 + 3] = cx + b3;
}

extern "C" void kernel_launch(void* const* d_in, const int* in_sizes, int n_in,
                              void* d_out, int out_size, void* d_ws, size_t ws_size,
                              hipStream_t stream)
{
    const float* x       = (const float*)d_in[0];
    const float* conv_w  = (const float*)d_in[1];
    const float* conv_b  = (const float*)d_in[2];
    const float* score_w = (const float*)d_in[3];
    const float* score_b = (const float*)d_in[4];
    const float* loc_w   = (const float*)d_in[5];
    const float* loc_b   = (const float*)d_in[6];
    const int*   img_h   = (const int*)d_in[7];
    const int*   img_w   = (const int*)d_in[8];

    float* out        = (float*)d_out;
    float* out_locs   = out;
    float* out_scores = out + 589824;
    float* out_roi    = out + 884736;
    float* out_anch   = out + 892736;

    char* ws = (char*)d_ws;
    float*    ht     = (float*)(ws + WS_HT);
    unsigned* key    = (unsigned*)(ws + WS_KEY);
    float*    wT     = (float*)(ws + WS_WT);
    double*   fgd    = (double*)(ws + WS_FGD);
    unsigned* hist1  = (unsigned*)(ws + WS_HIST1);
    unsigned* hist2  = (unsigned*)(ws + WS_HIST2);
    unsigned* rankp  = (unsigned*)(ws + WS_RANK);
    unsigned* ctrl   = (unsigned*)(ws + WS_CTRL);
    unsigned* seli   = (unsigned*)(ws + WS_SELI);
    double*   seld   = (double*)(ws + WS_SELD);
    unsigned* sorted = (unsigned*)(ws + WS_SORT);
    float*    boxes  = (float*)(ws + WS_BOX);
    float*    area   = (float*)(ws + WS_AREA);
    unsigned* valid  = (unsigned*)(ws + WS_VALID);
    unsigned long long* keepw = (unsigned long long*)(ws + WS_KEEP);
    unsigned long long* mask  = (unsigned long long*)(ws + WS_MASK);  // overlays HT

    hipMemsetAsync(ws + WS_ZERO0, 0, WS_ZEND - WS_ZERO0, stream);

    conv3_k<<<dim3(64, 16), 256, 0, stream>>>(x, conv_w, conv_b, ht);
    wt_build_k<<<128, 256, 0, stream>>>(loc_w, score_w, wT);
    head_k<<<2048, 256, 0, stream>>>(ht, wT, loc_b, score_b, out_locs, out_scores, fgd, key);
    hist1_k<<<576, 256, 0, stream>>>(key, hist1);
    scan_k<<<1, 256, 0, stream>>>(hist1, ctrl, 0);
    hist2_k<<<576, 256, 0, stream>>>(key, ctrl, hist2);
    scan_k<<<1, 256, 0, stream>>>(hist2, ctrl, 1);
    compact_k<<<576, 256, 0, stream>>>(key, fgd, ctrl, seli, seld);
    rankpart_k<<<dim3(64, 16), 256, 0, stream>>>(ctrl, seli, seld, rankp);
    scatter2_k<<<64, 256, 0, stream>>>(ctrl, seli, rankp, sorted);
    box_k<<<47, 256, 0, stream>>>(sorted, out_locs, img_h, img_w, boxes, area, valid);
    mask_k<<<dim3(NW, NW), 64, 0, stream>>>(boxes, area, valid, mask);
    nmsreduce_k<<<1, 256, 0, stream>>>(mask, valid, keepw);
    out_k<<<1, 256, 0, stream>>>(keepw, boxes, out_roi);
    anchors_k<<<576, 256, 0, stream>>>(out_anch);
}